// Round 4
// baseline (1388.285 us; speedup 1.0000x reference)
//
#include <hip/hip_runtime.h>
#include <hip/hip_bf16.h>

#define NN     50000
#define NEDGE  1600000
#define NG     512
#define FIN    128
#define FHID   128
#define FPROJ  256

typedef __attribute__((ext_vector_type(8))) short short8;
typedef __attribute__((ext_vector_type(4))) float f32x4;

static __device__ __forceinline__ short f2bf(float f) {
    union { float f; unsigned u; } x; x.f = f;
    unsigned r = (x.u + 0x7FFFu + ((x.u >> 16) & 1u)) >> 16;
    return (short)(r & 0xFFFFu);
}
static __device__ __forceinline__ float bf2f(unsigned short u) {
    union { unsigned u; float f; } x; x.u = ((unsigned)u) << 16;
    return x.f;
}
// nontemporal helpers (nt bit: no L2 allocate — keep streams out of L2)
static __device__ __forceinline__ int nt_ld_i(const int* p) {
    return __builtin_nontemporal_load(p);
}
static __device__ __forceinline__ float2 nt_ld_f2(const float* p) {
    union { unsigned long long u; float2 f; } c;
    c.u = __builtin_nontemporal_load((const unsigned long long*)p);
    return c.f;
}
static __device__ __forceinline__ void nt_st_f2(float* p, float2 v) {
    union { unsigned long long u; float2 f; } c; c.f = v;
    __builtin_nontemporal_store(c.u, (unsigned long long*)p);
}
static __device__ __forceinline__ f32x4 nt_ld_f4(const float* p) {
    return __builtin_nontemporal_load((const f32x4*)p);
}

// ---------------- CSR build ----------------

__global__ void k_histrank(const int* __restrict__ dst, int* __restrict__ cnt,
                           unsigned short* __restrict__ rank) {
    int i = blockIdx.x * 256 + threadIdx.x;
    if (i < NEDGE) rank[i] = (unsigned short)atomicAdd(&cnt[nt_ld_i(dst + i)], 1);
}

__global__ void k_scan1(const int* __restrict__ cnt, int* __restrict__ off,
                        int* __restrict__ bsum) {
    __shared__ int s[256];
    int i = blockIdx.x * 256 + threadIdx.x;
    int v = (i < NN) ? cnt[i] : 0;
    s[threadIdx.x] = v;
    for (int o = 1; o < 256; o <<= 1) {
        __syncthreads();
        int t = (threadIdx.x >= o) ? s[threadIdx.x - o] : 0;
        __syncthreads();
        s[threadIdx.x] += t;
    }
    __syncthreads();
    if (i < NN) off[i] = s[threadIdx.x] - v;              // exclusive
    if (threadIdx.x == 255) bsum[blockIdx.x] = s[255];
}

__global__ void k_scan2(int* __restrict__ bsum, int nb) {
    __shared__ int s[256];
    int v = (threadIdx.x < nb) ? bsum[threadIdx.x] : 0;
    s[threadIdx.x] = v;
    for (int o = 1; o < 256; o <<= 1) {
        __syncthreads();
        int t = (threadIdx.x >= o) ? s[threadIdx.x - o] : 0;
        __syncthreads();
        s[threadIdx.x] += t;
    }
    __syncthreads();
    if (threadIdx.x < nb) bsum[threadIdx.x] = s[threadIdx.x] - v;  // exclusive
}

__global__ void k_scan3(int* __restrict__ off, const int* __restrict__ bsum,
                        const int* __restrict__ cnt, float* __restrict__ dinv) {
    int i = blockIdx.x * 256 + threadIdx.x;
    if (i < NN) {
        off[i] += bsum[blockIdx.x];
        dinv[i] = 1.0f / sqrtf((float)(cnt[i] + 1));  // deg = in-deg + self-loop
    }
    if (i == 0) off[NN] = NEDGE;
}

__global__ void k_scatter(const int* __restrict__ src, const int* __restrict__ dst,
                          const int* __restrict__ off,
                          const unsigned short* __restrict__ rank,
                          int* __restrict__ csrc) {
    int i = blockIdx.x * 256 + threadIdx.x;
    if (i < NEDGE) {
        int d = nt_ld_i(dst + i);
        int r = (int)__builtin_nontemporal_load(rank + i);
        csrc[off[d] + r] = nt_ld_i(src + i);
    }
}

// ---------------- MFMA GEMM:  hp[i,:] = bf16( (A[i,:] @ W) * dinv[i] ) ----------------
// hp stored as FOUR 32-feature planes (3.2 MB each -> per-XCD-L2 resident):
//   hp[p*NN*32 + node*32 + cc]

__global__ void k_prepw(const float* __restrict__ W, short* __restrict__ Wf) {
    int nt = blockIdx.x >> 2, kt = blockIdx.x & 3;
    int lane = threadIdx.x;
    int n = nt * 16 + (lane & 15);
    int kbase = kt * 32 + (lane >> 4) * 8;
    short8 v;
#pragma unroll
    for (int j = 0; j < 8; ++j) v[j] = f2bf(W[(kbase + j) * FHID + n]);
    *(short8*)(Wf + (size_t)((nt * 4 + kt) * 64 + lane) * 8) = v;
}

__global__ __launch_bounds__(256) void k_gemm(const float* __restrict__ A,
                                              const short* __restrict__ Wf,
                                              const float* __restrict__ dinv,
                                              unsigned short* __restrict__ hp) {
    int lane = threadIdx.x & 63;
    int wv = threadIdx.x >> 6;
    int quad = lane >> 4;
    int rowbase = blockIdx.x * 64 + wv * 16;
    int arow = rowbase + (lane & 15);
    if (arow >= NN) arow = NN - 1;
    const float* Ap = A + (size_t)arow * FIN;

    f32x4 acc[8];
#pragma unroll
    for (int i = 0; i < 8; ++i) acc[i] = (f32x4){0.f, 0.f, 0.f, 0.f};

#pragma unroll
    for (int kt = 0; kt < 4; ++kt) {
        const float* ap = Ap + kt * 32 + quad * 8;
        f32x4 a0 = nt_ld_f4(ap);          // streamed once -> nt
        f32x4 a1 = nt_ld_f4(ap + 4);
        short8 af;
        af[0] = f2bf(a0[0]); af[1] = f2bf(a0[1]); af[2] = f2bf(a0[2]); af[3] = f2bf(a0[3]);
        af[4] = f2bf(a1[0]); af[5] = f2bf(a1[1]); af[6] = f2bf(a1[2]); af[7] = f2bf(a1[3]);
#pragma unroll
        for (int nt = 0; nt < 8; ++nt) {
            short8 bf = *(const short8*)(Wf + (size_t)((nt * 4 + kt) * 64 + lane) * 8);
            acc[nt] = __builtin_amdgcn_mfma_f32_16x16x32_bf16(af, bf, acc[nt], 0, 0, 0);
        }
    }
    // C/D layout: col = lane&15, row = quad*4 + reg   [measured m89/m91]
    float4 dv = *(const float4*)(dinv + rowbase + quad * 4);
    float dvv[4] = {dv.x, dv.y, dv.z, dv.w};
    int col = lane & 15;
#pragma unroll
    for (int r = 0; r < 4; ++r) {
        int orow = rowbase + quad * 4 + r;
        if (orow < NN) {
#pragma unroll
            for (int nt = 0; nt < 8; ++nt) {
                int plane = nt >> 1;
                int cc = ((nt & 1) << 4) + col;
                hp[(size_t)plane * NN * 32 + (size_t)orow * 32 + cc] =
                    (unsigned short)f2bf(acc[nt][r] * dvv[r]);
            }
        }
    }
}

// ------- Aggregate one 32-feature plane (hp plane L2-resident; streams are nt):
// hout[d, p*32:] = relu(dinv[d]*(hp_p[d]+sum_{s in N(d)} hp_p[s]) + b_p) [+resid]
// 16 lanes per node (2 bf16 feats per lane); 16 nodes per 256-thread block.

__global__ __launch_bounds__(256) void k_aggh32(const unsigned* __restrict__ hp,
                                                int plane,
                                                const int* __restrict__ off,
                                                const int* __restrict__ csrc,
                                                const float* __restrict__ dinv,
                                                const float* __restrict__ bias,
                                                const float* __restrict__ resid,
                                                float* __restrict__ hout) {
    int tid = threadIdx.x;
    int l2 = tid & 15;                            // 2 feats per lane -> 32 feats
    int node = blockIdx.x * 16 + (tid >> 4);      // 3125 blocks * 16 = 50000 exactly
    const unsigned* base = hp + (size_t)plane * NN * 16;
    int beg = off[node], end = off[node + 1];

    unsigned self = base[(size_t)node * 16 + l2];
    float a0 = bf2f((unsigned short)(self & 0xFFFFu));
    float a1 = bf2f((unsigned short)(self >> 16));

    int e = beg;
    for (; e + 8 <= end; e += 8) {
        int s0 = nt_ld_i(csrc + e + 0), s1 = nt_ld_i(csrc + e + 1);
        int s2 = nt_ld_i(csrc + e + 2), s3 = nt_ld_i(csrc + e + 3);
        int s4 = nt_ld_i(csrc + e + 4), s5 = nt_ld_i(csrc + e + 5);
        int s6 = nt_ld_i(csrc + e + 6), s7 = nt_ld_i(csrc + e + 7);
        unsigned v0 = base[(size_t)s0 * 16 + l2];
        unsigned v1 = base[(size_t)s1 * 16 + l2];
        unsigned v2 = base[(size_t)s2 * 16 + l2];
        unsigned v3 = base[(size_t)s3 * 16 + l2];
        unsigned v4 = base[(size_t)s4 * 16 + l2];
        unsigned v5 = base[(size_t)s5 * 16 + l2];
        unsigned v6 = base[(size_t)s6 * 16 + l2];
        unsigned v7 = base[(size_t)s7 * 16 + l2];
        a0 += bf2f((unsigned short)(v0 & 0xFFFFu)) + bf2f((unsigned short)(v1 & 0xFFFFu))
            + bf2f((unsigned short)(v2 & 0xFFFFu)) + bf2f((unsigned short)(v3 & 0xFFFFu))
            + bf2f((unsigned short)(v4 & 0xFFFFu)) + bf2f((unsigned short)(v5 & 0xFFFFu))
            + bf2f((unsigned short)(v6 & 0xFFFFu)) + bf2f((unsigned short)(v7 & 0xFFFFu));
        a1 += bf2f((unsigned short)(v0 >> 16)) + bf2f((unsigned short)(v1 >> 16))
            + bf2f((unsigned short)(v2 >> 16)) + bf2f((unsigned short)(v3 >> 16))
            + bf2f((unsigned short)(v4 >> 16)) + bf2f((unsigned short)(v5 >> 16))
            + bf2f((unsigned short)(v6 >> 16)) + bf2f((unsigned short)(v7 >> 16));
    }
    for (; e < end; ++e) {
        unsigned v = base[(size_t)nt_ld_i(csrc + e) * 16 + l2];
        a0 += bf2f((unsigned short)(v & 0xFFFFu));
        a1 += bf2f((unsigned short)(v >> 16));
    }
    float dv = dinv[node];
    float2 b = ((const float2*)bias)[plane * 16 + l2];
    float o0 = fmaxf(a0 * dv + b.x, 0.f);
    float o1 = fmaxf(a1 * dv + b.y, 0.f);
    if (resid) {
        float2 rr = nt_ld_f2(resid + (size_t)node * FHID + plane * 32 + 2 * l2);
        o0 += rr.x; o1 += rr.y;
    }
    nt_st_f2(hout + (size_t)node * FHID + plane * 32 + 2 * l2, make_float2(o0, o1));
}

// ---------------- Pooling ----------------

__global__ void k_starts(const int* __restrict__ batch, int* __restrict__ starts) {
    int i = blockIdx.x * 256 + threadIdx.x;
    if (i >= NN) return;
    int b = batch[i];
    if (i == 0) {
        for (int g = 0; g <= b; ++g) starts[g] = 0;
    } else {
        int p = batch[i - 1];
        for (int g = p + 1; g <= b; ++g) starts[g] = i;
    }
    if (i == NN - 1) {
        for (int g = b + 1; g <= NG; ++g) starts[g] = NN;
    }
}

__global__ void k_pool(const float* __restrict__ h, const int* __restrict__ starts,
                       float* __restrict__ pooled) {
    int g = blockIdx.x, c = threadIdx.x;
    int beg = starts[g], end = starts[g + 1];
    float s = 0.f;
    for (int i = beg; i < end; ++i)
        s += __builtin_nontemporal_load(h + (size_t)i * FHID + c);
    int cnt = end - beg;
    pooled[g * FHID + c] = s / (float)(cnt > 0 ? cnt : 1);
}

// ---------------- Fused MLP / BN heads (M = 512 rows) ----------------

__global__ void k_mlp(const float* __restrict__ A, const float* __restrict__ W,
                      const float* __restrict__ bias, float* __restrict__ out,
                      int K, int Nc, int act,
                      float* __restrict__ statsOut,
                      const float* __restrict__ statsIn,
                      const float* __restrict__ gIn, const float* __restrict__ beIn) {
    __shared__ float As[8 * 256];
    __shared__ float scl[256], shf[256];
    int n = threadIdx.x;                 // blockDim.x == Nc
    int r0 = blockIdx.x * 8;
    if (statsIn && n < K) {
        float m = statsIn[n] * (1.f / 512.f);
        float var = statsIn[K + n] * (1.f / 512.f) - m * m;
        float inv = 1.0f / sqrtf(var + 1e-5f);
        float s = gIn[n] * inv;
        scl[n] = s;
        shf[n] = beIn[n] - m * s;
    }
    __syncthreads();
    for (int idx = n; idx < 8 * K; idx += blockDim.x) {
        float v = A[(size_t)r0 * K + idx];
        if (statsIn) {
            int k = idx & (K - 1);       // K is 128 or 256
            v = fmaxf(v * scl[k] + shf[k], 0.f);   // relu(BN(.)) input transform
        }
        As[idx] = v;
    }
    __syncthreads();
    float bb = bias[n];
    float acc[8];
#pragma unroll
    for (int r = 0; r < 8; ++r) acc[r] = bb;
    for (int k = 0; k < K; ++k) {
        float w = W[(size_t)k * Nc + n];
#pragma unroll
        for (int r = 0; r < 8; ++r) acc[r] = fmaf(As[r * K + k], w, acc[r]);
    }
    if (statsOut) {
        float s = 0.f, q = 0.f;
#pragma unroll
        for (int r = 0; r < 8; ++r) { s += acc[r]; q += acc[r] * acc[r]; }
        atomicAdd(&statsOut[n], s);
        atomicAdd(&statsOut[Nc + n], q);
    }
#pragma unroll
    for (int r = 0; r < 8; ++r) {
        float v = acc[r];
        if (act) v = fmaxf(v, 0.f);
        out[(size_t)(r0 + r) * Nc + n] = v;
    }
}

__global__ void k_bnapply(const float* __restrict__ X, const float* __restrict__ stats,
                          const float* __restrict__ gamma, const float* __restrict__ beta,
                          float* __restrict__ out, int Nc, int act) {
    int i = blockIdx.x * 256 + threadIdx.x;
    if (i >= 512 * Nc) return;
    int c = i % Nc;
    float m = stats[c] * (1.f / 512.f);
    float var = stats[Nc + c] * (1.f / 512.f) - m * m;
    float inv = 1.0f / sqrtf(var + 1e-5f);
    float v = gamma[c] * (X[i] - m) * inv + beta[c];
    if (act) v = fmaxf(v, 0.f);
    out[i] = v;
}

// ---------------- Orchestration ----------------

extern "C" void kernel_launch(void* const* d_in, const int* in_sizes, int n_in,
                              void* d_out, int out_size, void* d_ws, size_t ws_size,
                              hipStream_t stream) {
    const float* x[2]     = {(const float*)d_in[0], (const float*)d_in[3]};
    const int*   ei[2]    = {(const int*)d_in[1], (const int*)d_in[4]};
    const int*   batch[2] = {(const int*)d_in[2], (const int*)d_in[5]};
    const float* W[3]  = {(const float*)d_in[6], (const float*)d_in[8], (const float*)d_in[10]};
    const float* bb[3] = {(const float*)d_in[7], (const float*)d_in[9], (const float*)d_in[11]};
    const float* Wp1 = (const float*)d_in[12]; const float* bp1 = (const float*)d_in[13];
    const float* g1  = (const float*)d_in[14]; const float* be1 = (const float*)d_in[15];
    const float* Wp2 = (const float*)d_in[16]; const float* bp2 = (const float*)d_in[17];
    const float* g2  = (const float*)d_in[18]; const float* be2 = (const float*)d_in[19];
    const float* Wq1 = (const float*)d_in[20]; const float* bq1 = (const float*)d_in[21];
    const float* Wq2 = (const float*)d_in[22]; const float* bq2 = (const float*)d_in[23];

    char* ws = (char*)d_ws;
    size_t off = 0;
    auto alloc = [&](size_t bytes) -> void* {
        void* p = ws + off;
        off += (bytes + 255) & ~(size_t)255;
        return p;
    };
    float*          h_cur  = (float*)alloc((size_t)NN * FHID * 4);
    unsigned short* hp     = (unsigned short*)alloc((size_t)NN * FHID * 2);
    int*            csrc   = (int*)alloc((size_t)NEDGE * 4);
    int*            csroff = (int*)alloc((size_t)(NN + 1) * 4);
    int*            cnt    = (int*)alloc((size_t)NN * 4);
    unsigned short* rank   = (unsigned short*)alloc((size_t)NEDGE * 2);
    float*          dinv   = (float*)alloc((size_t)50048 * 4);   // padded for gemm epilogue
    int*            bsum   = (int*)alloc(256 * 4);
    int*            starts = (int*)alloc((NG + 1) * 4);
    float*          pooled = (float*)alloc((size_t)2 * NG * FHID * 4);
    short*          Wf     = (short*)alloc((size_t)3 * 16384 * 2);
    float*          t1     = (float*)alloc((size_t)512 * 256 * 4);
    float*          t2     = (float*)alloc((size_t)512 * 256 * 4);
    float*          t3     = (float*)alloc((size_t)512 * 128 * 4);
    float*          stats  = (float*)alloc(4 * 256 * 4);  // [BN1: 256s+256q][BN2: 256s+256q]

    for (int l = 0; l < 3; ++l)
        k_prepw<<<32, 64, 0, stream>>>(W[l], Wf + (size_t)l * 16384);

    for (int e = 0; e < 2; ++e) {
        hipMemsetAsync(cnt, 0, (size_t)NN * 4, stream);
        const int* src = ei[e];
        const int* dst = ei[e] + NEDGE;
        k_histrank<<<(NEDGE + 255) / 256, 256, 0, stream>>>(dst, cnt, rank);
        k_scan1<<<196, 256, 0, stream>>>(cnt, csroff, bsum);
        k_scan2<<<1, 256, 0, stream>>>(bsum, 196);
        k_scan3<<<196, 256, 0, stream>>>(csroff, bsum, cnt, dinv);
        k_scatter<<<(NEDGE + 255) / 256, 256, 0, stream>>>(src, dst, csroff, rank, csrc);

        for (int l = 0; l < 3; ++l) {
            const float* Ain = (l == 0) ? x[e] : h_cur;
            const float* resid = (l == 0) ? nullptr : h_cur;
            k_gemm<<<782, 256, 0, stream>>>(Ain, Wf + (size_t)l * 16384, dinv, hp);
            for (int p = 0; p < 4; ++p)
                k_aggh32<<<3125, 256, 0, stream>>>((const unsigned*)hp, p, csroff, csrc,
                                                   dinv, bb[l], resid, h_cur);
        }
        k_starts<<<196, 256, 0, stream>>>(batch[e], starts);
        k_pool<<<NG, 128, 0, stream>>>(h_cur, starts, pooled + (size_t)e * NG * FHID);
    }

    float* outp = (float*)d_out;
    for (int e = 0; e < 2; ++e) {
        float* p_out = outp + (size_t)e * NG * FPROJ;
        float* z_out = outp + (size_t)(2 + e) * NG * FPROJ;
        float* st1 = stats, *st2 = stats + 512;
        hipMemsetAsync(stats, 0, 4 * 256 * 4, stream);
        // t1 = pooled @ Wp1 + bp1 (raw) ; accumulate BN1 stats
        k_mlp<<<64, 256, 0, stream>>>(pooled + (size_t)e * NG * FHID, Wp1, bp1, t1,
                                      128, 256, 0, st1, nullptr, nullptr, nullptr);
        // t2 = relu(BN1(t1)) @ Wp2 + bp2 (raw) ; accumulate BN2 stats
        k_mlp<<<64, 256, 0, stream>>>(t1, Wp2, bp2, t2,
                                      256, 256, 0, st2, st1, g1, be1);
        // z = BN2(t2)
        k_bnapply<<<512, 256, 0, stream>>>(t2, st2, g2, be2, z_out, 256, 0);
        // predictor
        k_mlp<<<64, 128, 0, stream>>>(z_out, Wq1, bq1, t3,
                                      256, 128, 1, nullptr, nullptr, nullptr, nullptr);
        k_mlp<<<64, 256, 0, stream>>>(t3, Wq2, bq2, p_out,
                                      128, 256, 0, nullptr, nullptr, nullptr, nullptr);
    }
}

// Round 5
// 986.073 us; speedup vs baseline: 1.4079x; 1.4079x over previous
//
#include <hip/hip_runtime.h>
#include <hip/hip_bf16.h>

#define NN     50000
#define NEDGE  1600000
#define NG     512
#define FIN    128
#define FHID   128
#define FPROJ  256

typedef __attribute__((ext_vector_type(8))) short short8;
typedef __attribute__((ext_vector_type(4))) float f32x4;

static __device__ __forceinline__ short f2bf(float f) {
    union { float f; unsigned u; } x; x.f = f;
    unsigned r = (x.u + 0x7FFFu + ((x.u >> 16) & 1u)) >> 16;
    return (short)(r & 0xFFFFu);
}
static __device__ __forceinline__ float bf2f(unsigned short u) {
    union { unsigned u; float f; } x; x.u = ((unsigned)u) << 16;
    return x.f;
}
static __device__ __forceinline__ float bflo(unsigned u) {
    union { unsigned u; float f; } x; x.u = u << 16; return x.f;
}
static __device__ __forceinline__ float bfhi(unsigned u) {
    union { unsigned u; float f; } x; x.u = u & 0xFFFF0000u; return x.f;
}
static __device__ __forceinline__ unsigned packbf(float a, float b) {
    return (unsigned)(unsigned short)f2bf(a) | ((unsigned)(unsigned short)f2bf(b) << 16);
}

// ---------------- CSR build ----------------

__global__ void k_histrank(const int* __restrict__ dst, int* __restrict__ cnt,
                           unsigned short* __restrict__ rank) {
    int i = blockIdx.x * 256 + threadIdx.x;
    if (i < NEDGE) rank[i] = (unsigned short)atomicAdd(&cnt[dst[i]], 1);
}

__global__ void k_scan1(const int* __restrict__ cnt, int* __restrict__ off,
                        int* __restrict__ bsum) {
    __shared__ int s[256];
    int i = blockIdx.x * 256 + threadIdx.x;
    int v = (i < NN) ? cnt[i] : 0;
    s[threadIdx.x] = v;
    for (int o = 1; o < 256; o <<= 1) {
        __syncthreads();
        int t = (threadIdx.x >= o) ? s[threadIdx.x - o] : 0;
        __syncthreads();
        s[threadIdx.x] += t;
    }
    __syncthreads();
    if (i < NN) off[i] = s[threadIdx.x] - v;              // exclusive
    if (threadIdx.x == 255) bsum[blockIdx.x] = s[255];
}

__global__ void k_scan2(int* __restrict__ bsum, int nb) {
    __shared__ int s[256];
    int v = (threadIdx.x < nb) ? bsum[threadIdx.x] : 0;
    s[threadIdx.x] = v;
    for (int o = 1; o < 256; o <<= 1) {
        __syncthreads();
        int t = (threadIdx.x >= o) ? s[threadIdx.x - o] : 0;
        __syncthreads();
        s[threadIdx.x] += t;
    }
    __syncthreads();
    if (threadIdx.x < nb) bsum[threadIdx.x] = s[threadIdx.x] - v;  // exclusive
}

__global__ void k_scan3(int* __restrict__ off, const int* __restrict__ bsum,
                        const int* __restrict__ cnt, float* __restrict__ dinv) {
    int i = blockIdx.x * 256 + threadIdx.x;
    if (i < NN) {
        off[i] += bsum[blockIdx.x];
        dinv[i] = 1.0f / sqrtf((float)(cnt[i] + 1));  // deg = in-deg + self-loop
    }
    if (i == 0) off[NN] = NEDGE;
}

__global__ void k_scatter(const int* __restrict__ src, const int* __restrict__ dst,
                          const int* __restrict__ off,
                          const unsigned short* __restrict__ rank,
                          int* __restrict__ csrc) {
    int i = blockIdx.x * 256 + threadIdx.x;
    if (i < NEDGE) csrc[off[dst[i]] + (int)rank[i]] = src[i];
}

// ---------------- MFMA GEMM:  hp[i,:] = bf16( (A[i,:] @ W) * dinv[i] ) ----------------
// A is fp32 (layer 0: x) or bf16 (layers 1-2: h_cur)

__global__ void k_prepw(const float* __restrict__ W, short* __restrict__ Wf) {
    int nt = blockIdx.x >> 2, kt = blockIdx.x & 3;
    int lane = threadIdx.x;
    int n = nt * 16 + (lane & 15);
    int kbase = kt * 32 + (lane >> 4) * 8;
    short8 v;
#pragma unroll
    for (int j = 0; j < 8; ++j) v[j] = f2bf(W[(kbase + j) * FHID + n]);
    *(short8*)(Wf + (size_t)((nt * 4 + kt) * 64 + lane) * 8) = v;
}

__global__ __launch_bounds__(256) void k_gemm(const float* __restrict__ Afp,
                                              const unsigned short* __restrict__ Abf,
                                              const short* __restrict__ Wf,
                                              const float* __restrict__ dinv,
                                              unsigned short* __restrict__ hp) {
    int lane = threadIdx.x & 63;
    int wv = threadIdx.x >> 6;
    int quad = lane >> 4;
    int rowbase = blockIdx.x * 64 + wv * 16;
    int arow = rowbase + (lane & 15);
    if (arow >= NN) arow = NN - 1;

    f32x4 acc[8];
#pragma unroll
    for (int i = 0; i < 8; ++i) acc[i] = (f32x4){0.f, 0.f, 0.f, 0.f};

#pragma unroll
    for (int kt = 0; kt < 4; ++kt) {
        short8 af;
        if (Abf) {
            af = *(const short8*)(Abf + (size_t)arow * FIN + kt * 32 + quad * 8);
        } else {
            const float* ap = Afp + (size_t)arow * FIN + kt * 32 + quad * 8;
            float4 a0 = *(const float4*)ap;
            float4 a1 = *(const float4*)(ap + 4);
            af[0] = f2bf(a0.x); af[1] = f2bf(a0.y); af[2] = f2bf(a0.z); af[3] = f2bf(a0.w);
            af[4] = f2bf(a1.x); af[5] = f2bf(a1.y); af[6] = f2bf(a1.z); af[7] = f2bf(a1.w);
        }
#pragma unroll
        for (int nt = 0; nt < 8; ++nt) {
            short8 bf = *(const short8*)(Wf + (size_t)((nt * 4 + kt) * 64 + lane) * 8);
            acc[nt] = __builtin_amdgcn_mfma_f32_16x16x32_bf16(af, bf, acc[nt], 0, 0, 0);
        }
    }
    // C/D layout: col = lane&15, row = quad*4 + reg   [measured m89/m91]
    float4 dv = *(const float4*)(dinv + rowbase + quad * 4);
    float dvv[4] = {dv.x, dv.y, dv.z, dv.w};
    int col = lane & 15;
#pragma unroll
    for (int r = 0; r < 4; ++r) {
        int orow = rowbase + quad * 4 + r;
        if (orow < NN) {
#pragma unroll
            for (int nt = 0; nt < 8; ++nt)
                hp[(size_t)orow * FHID + nt * 16 + col] =
                    (unsigned short)f2bf(acc[nt][r] * dvv[r]);
        }
    }
}

// ------- Aggregate full 128-feature row, single pass:
// hout[d,:] = bf16( relu(dinv[d]*(hp[d]+sum_{s in N(d)} hp[s]) + b) [+resid] )
// 32 lanes per node, dwordx2 (4 bf16 feats) per lane; 2 nodes per wave; 8 nodes/block.

__global__ __launch_bounds__(256) void k_agg(const uint2* __restrict__ hp,
                                             const int* __restrict__ off,
                                             const int* __restrict__ csrc,
                                             const float* __restrict__ dinv,
                                             const float* __restrict__ bias,
                                             const unsigned short* __restrict__ resid,
                                             unsigned short* __restrict__ hout) {
    int tid = threadIdx.x;
    int l2 = tid & 31;                        // 4 feats per lane -> 128 feats
    int node = blockIdx.x * 8 + (tid >> 5);   // 6250 blocks * 8 = 50000 exactly
    int beg = off[node], end = off[node + 1];

    uint2 sv = hp[(size_t)node * 32 + l2];
    float a0 = bflo(sv.x), a1 = bfhi(sv.x), a2 = bflo(sv.y), a3 = bfhi(sv.y);

    int e = beg;
    for (; e + 8 <= end; e += 8) {
        int s[8];
#pragma unroll
        for (int j = 0; j < 8; ++j) s[j] = csrc[e + j];
        uint2 v[8];
#pragma unroll
        for (int j = 0; j < 8; ++j) v[j] = hp[(size_t)s[j] * 32 + l2];
#pragma unroll
        for (int j = 0; j < 8; ++j) {
            a0 += bflo(v[j].x); a1 += bfhi(v[j].x);
            a2 += bflo(v[j].y); a3 += bfhi(v[j].y);
        }
    }
    for (; e < end; ++e) {
        uint2 v = hp[(size_t)csrc[e] * 32 + l2];
        a0 += bflo(v.x); a1 += bfhi(v.x);
        a2 += bflo(v.y); a3 += bfhi(v.y);
    }
    float dv = dinv[node];
    float4 b = ((const float4*)bias)[l2];
    float o0 = fmaxf(a0 * dv + b.x, 0.f);
    float o1 = fmaxf(a1 * dv + b.y, 0.f);
    float o2 = fmaxf(a2 * dv + b.z, 0.f);
    float o3 = fmaxf(a3 * dv + b.w, 0.f);
    if (resid) {
        uint2 rv = ((const uint2*)resid)[(size_t)node * 32 + l2];
        o0 += bflo(rv.x); o1 += bfhi(rv.x);
        o2 += bflo(rv.y); o3 += bfhi(rv.y);
    }
    uint2 ov;
    ov.x = packbf(o0, o1);
    ov.y = packbf(o2, o3);
    ((uint2*)hout)[(size_t)node * 32 + l2] = ov;
}

// ---------------- Pooling ----------------

__global__ void k_starts(const int* __restrict__ batch, int* __restrict__ starts) {
    int i = blockIdx.x * 256 + threadIdx.x;
    if (i >= NN) return;
    int b = batch[i];
    if (i == 0) {
        for (int g = 0; g <= b; ++g) starts[g] = 0;
    } else {
        int p = batch[i - 1];
        for (int g = p + 1; g <= b; ++g) starts[g] = i;
    }
    if (i == NN - 1) {
        for (int g = b + 1; g <= NG; ++g) starts[g] = NN;
    }
}

__global__ void k_pool(const unsigned short* __restrict__ h, const int* __restrict__ starts,
                       float* __restrict__ pooled) {
    int g = blockIdx.x, c = threadIdx.x;   // 128 threads
    int beg = starts[g], end = starts[g + 1];
    float s = 0.f;
    for (int i = beg; i < end; ++i) s += bf2f(h[(size_t)i * FHID + c]);
    int cnt = end - beg;
    pooled[g * FHID + c] = s / (float)(cnt > 0 ? cnt : 1);
}

// ---------------- Fused MLP / BN heads (M = 512 rows) ----------------

__global__ void k_mlp(const float* __restrict__ A, const float* __restrict__ W,
                      const float* __restrict__ bias, float* __restrict__ out,
                      int K, int Nc, int act,
                      float* __restrict__ statsOut,
                      const float* __restrict__ statsIn,
                      const float* __restrict__ gIn, const float* __restrict__ beIn) {
    __shared__ float As[8 * 256];
    __shared__ float scl[256], shf[256];
    int n = threadIdx.x;                 // blockDim.x == Nc
    int r0 = blockIdx.x * 8;
    if (statsIn && n < K) {
        float m = statsIn[n] * (1.f / 512.f);
        float var = statsIn[K + n] * (1.f / 512.f) - m * m;
        float inv = 1.0f / sqrtf(var + 1e-5f);
        float s = gIn[n] * inv;
        scl[n] = s;
        shf[n] = beIn[n] - m * s;
    }
    __syncthreads();
    for (int idx = n; idx < 8 * K; idx += blockDim.x) {
        float v = A[(size_t)r0 * K + idx];
        if (statsIn) {
            int k = idx & (K - 1);       // K is 128 or 256
            v = fmaxf(v * scl[k] + shf[k], 0.f);   // relu(BN(.)) input transform
        }
        As[idx] = v;
    }
    __syncthreads();
    float bb = bias[n];
    float acc[8];
#pragma unroll
    for (int r = 0; r < 8; ++r) acc[r] = bb;
    for (int k = 0; k < K; ++k) {
        float w = W[(size_t)k * Nc + n];
#pragma unroll
        for (int r = 0; r < 8; ++r) acc[r] = fmaf(As[r * K + k], w, acc[r]);
    }
    if (statsOut) {
        float s = 0.f, q = 0.f;
#pragma unroll
        for (int r = 0; r < 8; ++r) { s += acc[r]; q += acc[r] * acc[r]; }
        atomicAdd(&statsOut[n], s);
        atomicAdd(&statsOut[Nc + n], q);
    }
#pragma unroll
    for (int r = 0; r < 8; ++r) {
        float v = acc[r];
        if (act) v = fmaxf(v, 0.f);
        out[(size_t)(r0 + r) * Nc + n] = v;
    }
}

__global__ void k_bnapply(const float* __restrict__ X, const float* __restrict__ stats,
                          const float* __restrict__ gamma, const float* __restrict__ beta,
                          float* __restrict__ out, int Nc, int act) {
    int i = blockIdx.x * 256 + threadIdx.x;
    if (i >= 512 * Nc) return;
    int c = i % Nc;
    float m = stats[c] * (1.f / 512.f);
    float var = stats[Nc + c] * (1.f / 512.f) - m * m;
    float inv = 1.0f / sqrtf(var + 1e-5f);
    float v = gamma[c] * (X[i] - m) * inv + beta[c];
    if (act) v = fmaxf(v, 0.f);
    out[i] = v;
}

// ---------------- Orchestration ----------------

extern "C" void kernel_launch(void* const* d_in, const int* in_sizes, int n_in,
                              void* d_out, int out_size, void* d_ws, size_t ws_size,
                              hipStream_t stream) {
    const float* x[2]     = {(const float*)d_in[0], (const float*)d_in[3]};
    const int*   ei[2]    = {(const int*)d_in[1], (const int*)d_in[4]};
    const int*   batch[2] = {(const int*)d_in[2], (const int*)d_in[5]};
    const float* W[3]  = {(const float*)d_in[6], (const float*)d_in[8], (const float*)d_in[10]};
    const float* bb[3] = {(const float*)d_in[7], (const float*)d_in[9], (const float*)d_in[11]};
    const float* Wp1 = (const float*)d_in[12]; const float* bp1 = (const float*)d_in[13];
    const float* g1  = (const float*)d_in[14]; const float* be1 = (const float*)d_in[15];
    const float* Wp2 = (const float*)d_in[16]; const float* bp2 = (const float*)d_in[17];
    const float* g2  = (const float*)d_in[18]; const float* be2 = (const float*)d_in[19];
    const float* Wq1 = (const float*)d_in[20]; const float* bq1 = (const float*)d_in[21];
    const float* Wq2 = (const float*)d_in[22]; const float* bq2 = (const float*)d_in[23];

    char* ws = (char*)d_ws;
    size_t off = 0;
    auto alloc = [&](size_t bytes) -> void* {
        void* p = ws + off;
        off += (bytes + 255) & ~(size_t)255;
        return p;
    };
    unsigned short* h_cur  = (unsigned short*)alloc((size_t)NN * FHID * 2);  // bf16 state
    unsigned short* hp     = (unsigned short*)alloc((size_t)NN * FHID * 2);  // bf16 pre-agg
    int*            csrc   = (int*)alloc((size_t)NEDGE * 4);
    int*            csroff = (int*)alloc((size_t)(NN + 1) * 4);
    int*            cnt    = (int*)alloc((size_t)NN * 4);
    unsigned short* rank   = (unsigned short*)alloc((size_t)NEDGE * 2);
    float*          dinv   = (float*)alloc((size_t)50048 * 4);   // padded for gemm epilogue
    int*            bsum   = (int*)alloc(256 * 4);
    int*            starts = (int*)alloc((NG + 1) * 4);
    float*          pooled = (float*)alloc((size_t)2 * NG * FHID * 4);
    short*          Wf     = (short*)alloc((size_t)3 * 16384 * 2);
    float*          t1     = (float*)alloc((size_t)512 * 256 * 4);
    float*          t2     = (float*)alloc((size_t)512 * 256 * 4);
    float*          t3     = (float*)alloc((size_t)512 * 128 * 4);
    float*          stats  = (float*)alloc(4 * 256 * 4);  // [BN1: 256s+256q][BN2: 256s+256q]

    for (int l = 0; l < 3; ++l)
        k_prepw<<<32, 64, 0, stream>>>(W[l], Wf + (size_t)l * 16384);

    for (int e = 0; e < 2; ++e) {
        hipMemsetAsync(cnt, 0, (size_t)NN * 4, stream);
        const int* src = ei[e];
        const int* dst = ei[e] + NEDGE;
        k_histrank<<<(NEDGE + 255) / 256, 256, 0, stream>>>(dst, cnt, rank);
        k_scan1<<<196, 256, 0, stream>>>(cnt, csroff, bsum);
        k_scan2<<<1, 256, 0, stream>>>(bsum, 196);
        k_scan3<<<196, 256, 0, stream>>>(csroff, bsum, cnt, dinv);
        k_scatter<<<(NEDGE + 255) / 256, 256, 0, stream>>>(src, dst, csroff, rank, csrc);

        for (int l = 0; l < 3; ++l) {
            const float* Afp = (l == 0) ? x[e] : nullptr;
            const unsigned short* Abf = (l == 0) ? nullptr : h_cur;
            const unsigned short* resid = (l == 0) ? nullptr : h_cur;
            k_gemm<<<782, 256, 0, stream>>>(Afp, Abf, Wf + (size_t)l * 16384, dinv, hp);
            k_agg<<<6250, 256, 0, stream>>>((const uint2*)hp, csroff, csrc, dinv,
                                            bb[l], resid, h_cur);
        }
        k_starts<<<196, 256, 0, stream>>>(batch[e], starts);
        k_pool<<<NG, 128, 0, stream>>>(h_cur, starts, pooled + (size_t)e * NG * FHID);
    }

    float* outp = (float*)d_out;
    for (int e = 0; e < 2; ++e) {
        float* p_out = outp + (size_t)e * NG * FPROJ;
        float* z_out = outp + (size_t)(2 + e) * NG * FPROJ;
        float* st1 = stats, *st2 = stats + 512;
        hipMemsetAsync(stats, 0, 4 * 256 * 4, stream);
        // t1 = pooled @ Wp1 + bp1 (raw) ; accumulate BN1 stats
        k_mlp<<<64, 256, 0, stream>>>(pooled + (size_t)e * NG * FHID, Wp1, bp1, t1,
                                      128, 256, 0, st1, nullptr, nullptr, nullptr);
        // t2 = relu(BN1(t1)) @ Wp2 + bp2 (raw) ; accumulate BN2 stats
        k_mlp<<<64, 256, 0, stream>>>(t1, Wp2, bp2, t2,
                                      256, 256, 0, st2, st1, g1, be1);
        // z = BN2(t2)
        k_bnapply<<<512, 256, 0, stream>>>(t2, st2, g2, be2, z_out, 256, 0);
        // predictor
        k_mlp<<<64, 128, 0, stream>>>(z_out, Wq1, bq1, t3,
                                      256, 128, 1, nullptr, nullptr, nullptr, nullptr);
        k_mlp<<<64, 256, 0, stream>>>(t3, Wq2, bq2, p_out,
                                      128, 256, 0, nullptr, nullptr, nullptr, nullptr);
    }
}

// Round 6
// 902.082 us; speedup vs baseline: 1.5390x; 1.0931x over previous
//
#include <hip/hip_runtime.h>
#include <hip/hip_bf16.h>

#define NN     50000
#define NEDGE  1600000
#define NG     512
#define FIN    128
#define FHID   128
#define FPROJ  256

// radix CSR build params
#define NBUCK  782            // ceil(50000/64) buckets of 64 nodes (dst>>6)
#define EPB    8192           // edges per A-phase block
#define NABLK  196            // ceil(NEDGE/EPB)
#define NHIST  (NBUCK*NABLK)  // 153,272

typedef __attribute__((ext_vector_type(8))) short short8;
typedef __attribute__((ext_vector_type(4))) float f32x4;

static __device__ __forceinline__ short f2bf(float f) {
    union { float f; unsigned u; } x; x.f = f;
    unsigned r = (x.u + 0x7FFFu + ((x.u >> 16) & 1u)) >> 16;
    return (short)(r & 0xFFFFu);
}
static __device__ __forceinline__ float bf2f(unsigned short u) {
    union { unsigned u; float f; } x; x.u = ((unsigned)u) << 16;
    return x.f;
}
static __device__ __forceinline__ float bflo(unsigned u) {
    union { unsigned u; float f; } x; x.u = u << 16; return x.f;
}
static __device__ __forceinline__ float bfhi(unsigned u) {
    union { unsigned u; float f; } x; x.u = u & 0xFFFF0000u; return x.f;
}
static __device__ __forceinline__ unsigned packbf(float a, float b) {
    return (unsigned)(unsigned short)f2bf(a) | ((unsigned)(unsigned short)f2bf(b) << 16);
}

// ---------------- CSR build (atomic-free at device scope) ----------------

// A1: per-block LDS histogram over 782 coarse buckets + per-edge local rank
__global__ __launch_bounds__(1024) void k_bhist(const int* __restrict__ dst,
                                                int* __restrict__ histG,
                                                unsigned short* __restrict__ lrank) {
    __shared__ int h[NBUCK];
    for (int j = threadIdx.x; j < NBUCK; j += 1024) h[j] = 0;
    __syncthreads();
    int base = blockIdx.x * EPB;
    for (int t = threadIdx.x; t < EPB; t += 1024) {
        int i = base + t;
        if (i < NEDGE)
            lrank[i] = (unsigned short)atomicAdd(&h[dst[i] >> 6], 1);
    }
    __syncthreads();
    for (int j = threadIdx.x; j < NBUCK; j += 1024)
        histG[j * NABLK + blockIdx.x] = h[j];
}

// generic 256-block exclusive scan + block sums
__global__ void s_scan256(const int* __restrict__ in, int* __restrict__ out,
                          int* __restrict__ bsum, int n) {
    __shared__ int s[256];
    int i = blockIdx.x * 256 + threadIdx.x;
    int v = (i < n) ? in[i] : 0;
    s[threadIdx.x] = v;
    for (int o = 1; o < 256; o <<= 1) {
        __syncthreads();
        int t = (threadIdx.x >= o) ? s[threadIdx.x - o] : 0;
        __syncthreads();
        s[threadIdx.x] += t;
    }
    __syncthreads();
    if (i < n) out[i] = s[threadIdx.x] - v;   // exclusive
    if (threadIdx.x == 255 && bsum) bsum[blockIdx.x] = s[255];
}

__global__ void s_add(int* __restrict__ out, const int* __restrict__ bs, int n) {
    int i = blockIdx.x * 256 + threadIdx.x;
    if (i < n) out[i] += bs[blockIdx.x];
}

// A3: partition edges into bucket-major pedge (plain stores, unique positions)
__global__ __launch_bounds__(1024) void k_part(const int* __restrict__ src,
                                               const int* __restrict__ dst,
                                               const unsigned short* __restrict__ lrank,
                                               const int* __restrict__ histS,
                                               unsigned* __restrict__ pedge) {
    int base = blockIdx.x * EPB;
    for (int t = threadIdx.x; t < EPB; t += 1024) {
        int i = base + t;
        if (i < NEDGE) {
            int d = dst[i];
            int pos = histS[(d >> 6) * NABLK + blockIdx.x] + (int)lrank[i];
            pedge[pos] = (unsigned)src[i] | ((unsigned)(d & 63) << 16);
        }
    }
}

// B: one block per 64-node bucket -> fine CSR + csroff + dinv (LDS atomics only)
__global__ __launch_bounds__(256) void k_csr(const unsigned* __restrict__ pedge,
                                             const int* __restrict__ histS,
                                             int* __restrict__ csroff,
                                             int* __restrict__ csrc,
                                             float* __restrict__ dinv) {
    __shared__ int cnt[64], off[64], cur[64];
    int k = blockIdx.x;
    int beg = histS[k * NABLK];
    int end = (k == NBUCK - 1) ? NEDGE : histS[(k + 1) * NABLK];
    if (threadIdx.x < 64) { cnt[threadIdx.x] = 0; cur[threadIdx.x] = 0; }
    __syncthreads();
    for (int e = beg + threadIdx.x; e < end; e += 256)
        atomicAdd(&cnt[pedge[e] >> 16], 1);
    __syncthreads();
    if (threadIdx.x == 0) {
        int s = 0;
        for (int j = 0; j < 64; ++j) { off[j] = s; s += cnt[j]; }
    }
    __syncthreads();
    for (int e = beg + threadIdx.x; e < end; e += 256) {
        unsigned v = pedge[e];
        int j = v >> 16;
        int r = atomicAdd(&cur[j], 1);
        csrc[beg + off[j] + r] = (int)(v & 0xFFFFu);
    }
    if (threadIdx.x < 64) {
        int node = k * 64 + threadIdx.x;
        if (node < NN) {
            csroff[node] = beg + off[threadIdx.x];
            dinv[node] = 1.0f / sqrtf((float)(cnt[threadIdx.x] + 1));
        }
    }
    if (k == NBUCK - 1 && threadIdx.x == 0) csroff[NN] = NEDGE;
}

// ---------------- MFMA GEMM:  hp[i,:] = bf16( (A[i,:] @ W) * dinv[i] ) ----------------

__global__ void k_prepw(const float* __restrict__ W, short* __restrict__ Wf) {
    int nt = blockIdx.x >> 2, kt = blockIdx.x & 3;
    int lane = threadIdx.x;
    int n = nt * 16 + (lane & 15);
    int kbase = kt * 32 + (lane >> 4) * 8;
    short8 v;
#pragma unroll
    for (int j = 0; j < 8; ++j) v[j] = f2bf(W[(kbase + j) * FHID + n]);
    *(short8*)(Wf + (size_t)((nt * 4 + kt) * 64 + lane) * 8) = v;
}

__global__ __launch_bounds__(256) void k_gemm(const float* __restrict__ Afp,
                                              const unsigned short* __restrict__ Abf,
                                              const short* __restrict__ Wf,
                                              const float* __restrict__ dinv,
                                              unsigned short* __restrict__ hp) {
    int lane = threadIdx.x & 63;
    int wv = threadIdx.x >> 6;
    int quad = lane >> 4;
    int rowbase = blockIdx.x * 64 + wv * 16;
    int arow = rowbase + (lane & 15);
    if (arow >= NN) arow = NN - 1;

    f32x4 acc[8];
#pragma unroll
    for (int i = 0; i < 8; ++i) acc[i] = (f32x4){0.f, 0.f, 0.f, 0.f};

#pragma unroll
    for (int kt = 0; kt < 4; ++kt) {
        short8 af;
        if (Abf) {
            af = *(const short8*)(Abf + (size_t)arow * FIN + kt * 32 + quad * 8);
        } else {
            const float* ap = Afp + (size_t)arow * FIN + kt * 32 + quad * 8;
            float4 a0 = *(const float4*)ap;
            float4 a1 = *(const float4*)(ap + 4);
            af[0] = f2bf(a0.x); af[1] = f2bf(a0.y); af[2] = f2bf(a0.z); af[3] = f2bf(a0.w);
            af[4] = f2bf(a1.x); af[5] = f2bf(a1.y); af[6] = f2bf(a1.z); af[7] = f2bf(a1.w);
        }
#pragma unroll
        for (int nt = 0; nt < 8; ++nt) {
            short8 bf = *(const short8*)(Wf + (size_t)((nt * 4 + kt) * 64 + lane) * 8);
            acc[nt] = __builtin_amdgcn_mfma_f32_16x16x32_bf16(af, bf, acc[nt], 0, 0, 0);
        }
    }
    // C/D layout: col = lane&15, row = quad*4 + reg   [measured m89/m91]
    float4 dv = *(const float4*)(dinv + rowbase + quad * 4);
    float dvv[4] = {dv.x, dv.y, dv.z, dv.w};
    int col = lane & 15;
#pragma unroll
    for (int r = 0; r < 4; ++r) {
        int orow = rowbase + quad * 4 + r;
        if (orow < NN) {
#pragma unroll
            for (int nt = 0; nt < 8; ++nt)
                hp[(size_t)orow * FHID + nt * 16 + col] =
                    (unsigned short)f2bf(acc[nt][r] * dvv[r]);
        }
    }
}

// ------- Aggregate full 128-feature row, single pass (R5-verified structure)

__global__ __launch_bounds__(256) void k_agg(const uint2* __restrict__ hp,
                                             const int* __restrict__ off,
                                             const int* __restrict__ csrc,
                                             const float* __restrict__ dinv,
                                             const float* __restrict__ bias,
                                             const unsigned short* __restrict__ resid,
                                             unsigned short* __restrict__ hout) {
    int tid = threadIdx.x;
    int l2 = tid & 31;                        // 4 feats per lane -> 128 feats
    int node = blockIdx.x * 8 + (tid >> 5);   // 6250 blocks * 8 = 50000 exactly
    int beg = off[node], end = off[node + 1];

    uint2 sv = hp[(size_t)node * 32 + l2];
    float a0 = bflo(sv.x), a1 = bfhi(sv.x), a2 = bflo(sv.y), a3 = bfhi(sv.y);

    int e = beg;
    for (; e + 8 <= end; e += 8) {
        int s[8];
#pragma unroll
        for (int j = 0; j < 8; ++j) s[j] = csrc[e + j];
        uint2 v[8];
#pragma unroll
        for (int j = 0; j < 8; ++j) v[j] = hp[(size_t)s[j] * 32 + l2];
#pragma unroll
        for (int j = 0; j < 8; ++j) {
            a0 += bflo(v[j].x); a1 += bfhi(v[j].x);
            a2 += bflo(v[j].y); a3 += bfhi(v[j].y);
        }
    }
    for (; e < end; ++e) {
        uint2 v = hp[(size_t)csrc[e] * 32 + l2];
        a0 += bflo(v.x); a1 += bfhi(v.x);
        a2 += bflo(v.y); a3 += bfhi(v.y);
    }
    float dv = dinv[node];
    float4 b = ((const float4*)bias)[l2];
    float o0 = fmaxf(a0 * dv + b.x, 0.f);
    float o1 = fmaxf(a1 * dv + b.y, 0.f);
    float o2 = fmaxf(a2 * dv + b.z, 0.f);
    float o3 = fmaxf(a3 * dv + b.w, 0.f);
    if (resid) {
        uint2 rv = ((const uint2*)resid)[(size_t)node * 32 + l2];
        o0 += bflo(rv.x); o1 += bfhi(rv.x);
        o2 += bflo(rv.y); o3 += bfhi(rv.y);
    }
    uint2 ov;
    ov.x = packbf(o0, o1);
    ov.y = packbf(o2, o3);
    ((uint2*)hout)[(size_t)node * 32 + l2] = ov;
}

// ---------------- Pooling ----------------

__global__ void k_starts(const int* __restrict__ batch, int* __restrict__ starts) {
    int i = blockIdx.x * 256 + threadIdx.x;
    if (i >= NN) return;
    int b = batch[i];
    if (i == 0) {
        for (int g = 0; g <= b; ++g) starts[g] = 0;
    } else {
        int p = batch[i - 1];
        for (int g = p + 1; g <= b; ++g) starts[g] = i;
    }
    if (i == NN - 1) {
        for (int g = b + 1; g <= NG; ++g) starts[g] = NN;
    }
}

__global__ void k_pool(const unsigned short* __restrict__ h, const int* __restrict__ starts,
                       float* __restrict__ pooled) {
    int g = blockIdx.x, c = threadIdx.x;   // 128 threads
    int beg = starts[g], end = starts[g + 1];
    float s = 0.f;
    for (int i = beg; i < end; ++i) s += bf2f(h[(size_t)i * FHID + c]);
    int cnt = end - beg;
    pooled[g * FHID + c] = s / (float)(cnt > 0 ? cnt : 1);
}

// ---------------- Fused MLP / BN heads (M = 512 rows) ----------------

__global__ void k_mlp(const float* __restrict__ A, const float* __restrict__ W,
                      const float* __restrict__ bias, float* __restrict__ out,
                      int K, int Nc, int act,
                      float* __restrict__ statsOut,
                      const float* __restrict__ statsIn,
                      const float* __restrict__ gIn, const float* __restrict__ beIn) {
    __shared__ float As[8 * 256];
    __shared__ float scl[256], shf[256];
    int n = threadIdx.x;                 // blockDim.x == Nc
    int r0 = blockIdx.x * 8;
    if (statsIn && n < K) {
        float m = statsIn[n] * (1.f / 512.f);
        float var = statsIn[K + n] * (1.f / 512.f) - m * m;
        float inv = 1.0f / sqrtf(var + 1e-5f);
        float s = gIn[n] * inv;
        scl[n] = s;
        shf[n] = beIn[n] - m * s;
    }
    __syncthreads();
    for (int idx = n; idx < 8 * K; idx += blockDim.x) {
        float v = A[(size_t)r0 * K + idx];
        if (statsIn) {
            int k = idx & (K - 1);       // K is 128 or 256
            v = fmaxf(v * scl[k] + shf[k], 0.f);   // relu(BN(.)) input transform
        }
        As[idx] = v;
    }
    __syncthreads();
    float bb = bias[n];
    float acc[8];
#pragma unroll
    for (int r = 0; r < 8; ++r) acc[r] = bb;
    for (int k = 0; k < K; ++k) {
        float w = W[(size_t)k * Nc + n];
#pragma unroll
        for (int r = 0; r < 8; ++r) acc[r] = fmaf(As[r * K + k], w, acc[r]);
    }
    if (statsOut) {
        float s = 0.f, q = 0.f;
#pragma unroll
        for (int r = 0; r < 8; ++r) { s += acc[r]; q += acc[r] * acc[r]; }
        atomicAdd(&statsOut[n], s);
        atomicAdd(&statsOut[Nc + n], q);
    }
#pragma unroll
    for (int r = 0; r < 8; ++r) {
        float v = acc[r];
        if (act) v = fmaxf(v, 0.f);
        out[(size_t)(r0 + r) * Nc + n] = v;
    }
}

__global__ void k_bnapply(const float* __restrict__ X, const float* __restrict__ stats,
                          const float* __restrict__ gamma, const float* __restrict__ beta,
                          float* __restrict__ out, int Nc, int act) {
    int i = blockIdx.x * 256 + threadIdx.x;
    if (i >= 512 * Nc) return;
    int c = i % Nc;
    float m = stats[c] * (1.f / 512.f);
    float var = stats[Nc + c] * (1.f / 512.f) - m * m;
    float inv = 1.0f / sqrtf(var + 1e-5f);
    float v = gamma[c] * (X[i] - m) * inv + beta[c];
    if (act) v = fmaxf(v, 0.f);
    out[i] = v;
}

// ---------------- Orchestration ----------------

extern "C" void kernel_launch(void* const* d_in, const int* in_sizes, int n_in,
                              void* d_out, int out_size, void* d_ws, size_t ws_size,
                              hipStream_t stream) {
    const float* x[2]     = {(const float*)d_in[0], (const float*)d_in[3]};
    const int*   ei[2]    = {(const int*)d_in[1], (const int*)d_in[4]};
    const int*   batch[2] = {(const int*)d_in[2], (const int*)d_in[5]};
    const float* W[3]  = {(const float*)d_in[6], (const float*)d_in[8], (const float*)d_in[10]};
    const float* bb[3] = {(const float*)d_in[7], (const float*)d_in[9], (const float*)d_in[11]};
    const float* Wp1 = (const float*)d_in[12]; const float* bp1 = (const float*)d_in[13];
    const float* g1  = (const float*)d_in[14]; const float* be1 = (const float*)d_in[15];
    const float* Wp2 = (const float*)d_in[16]; const float* bp2 = (const float*)d_in[17];
    const float* g2  = (const float*)d_in[18]; const float* be2 = (const float*)d_in[19];
    const float* Wq1 = (const float*)d_in[20]; const float* bq1 = (const float*)d_in[21];
    const float* Wq2 = (const float*)d_in[22]; const float* bq2 = (const float*)d_in[23];

    char* ws = (char*)d_ws;
    size_t off = 0;
    auto alloc = [&](size_t bytes) -> void* {
        void* p = ws + off;
        off += (bytes + 255) & ~(size_t)255;
        return p;
    };
    unsigned short* h_cur  = (unsigned short*)alloc((size_t)NN * FHID * 2);  // bf16 state
    unsigned short* hp     = (unsigned short*)alloc((size_t)NN * FHID * 2);  // bf16 pre-agg
    int*            csrc   = (int*)alloc((size_t)NEDGE * 4);
    int*            csroff = (int*)alloc((size_t)(NN + 1) * 4);
    unsigned short* lrank  = (unsigned short*)alloc((size_t)NEDGE * 2);
    unsigned*       pedge  = (unsigned*)alloc((size_t)NEDGE * 4);
    int*            histG  = (int*)alloc((size_t)NHIST * 4);
    int*            histS  = (int*)alloc((size_t)NHIST * 4);
    int*            bsum1  = (int*)alloc(1024 * 4);
    int*            bsum1s = (int*)alloc(1024 * 4);
    int*            bsum2  = (int*)alloc(256 * 4);
    int*            bsum2s = (int*)alloc(256 * 4);
    float*          dinv   = (float*)alloc((size_t)50048 * 4);   // padded for gemm epilogue
    int*            starts = (int*)alloc((NG + 1) * 4);
    float*          pooled = (float*)alloc((size_t)2 * NG * FHID * 4);
    short*          Wf     = (short*)alloc((size_t)3 * 16384 * 2);
    float*          t1     = (float*)alloc((size_t)512 * 256 * 4);
    float*          t2     = (float*)alloc((size_t)512 * 256 * 4);
    float*          t3     = (float*)alloc((size_t)512 * 128 * 4);
    float*          stats  = (float*)alloc(4 * 256 * 4);  // [BN1: 256s+256q][BN2: 256s+256q]

    for (int l = 0; l < 3; ++l)
        k_prepw<<<32, 64, 0, stream>>>(W[l], Wf + (size_t)l * 16384);

    const int nsb1 = (NHIST + 255) / 256;          // 599 scan blocks
    const int nsb2 = (nsb1 + 255) / 256;           // 3

    for (int e = 0; e < 2; ++e) {
        const int* src = ei[e];
        const int* dst = ei[e] + NEDGE;
        // atomic-free radix CSR build
        k_bhist<<<NABLK, 1024, 0, stream>>>(dst, histG, lrank);
        s_scan256<<<nsb1, 256, 0, stream>>>(histG, histS, bsum1, NHIST);
        s_scan256<<<nsb2, 256, 0, stream>>>(bsum1, bsum1s, bsum2, nsb1);
        s_scan256<<<1, 256, 0, stream>>>(bsum2, bsum2s, nullptr, nsb2);
        s_add<<<nsb2, 256, 0, stream>>>(bsum1s, bsum2s, nsb1);
        s_add<<<nsb1, 256, 0, stream>>>(histS, bsum1s, NHIST);
        k_part<<<NABLK, 1024, 0, stream>>>(src, dst, lrank, histS, pedge);
        k_csr<<<NBUCK, 256, 0, stream>>>(pedge, histS, csroff, csrc, dinv);

        for (int l = 0; l < 3; ++l) {
            const float* Afp = (l == 0) ? x[e] : nullptr;
            const unsigned short* Abf = (l == 0) ? nullptr : h_cur;
            const unsigned short* resid = (l == 0) ? nullptr : h_cur;
            k_gemm<<<782, 256, 0, stream>>>(Afp, Abf, Wf + (size_t)l * 16384, dinv, hp);
            k_agg<<<6250, 256, 0, stream>>>((const uint2*)hp, csroff, csrc, dinv,
                                            bb[l], resid, h_cur);
        }
        k_starts<<<196, 256, 0, stream>>>(batch[e], starts);
        k_pool<<<NG, 128, 0, stream>>>(h_cur, starts, pooled + (size_t)e * NG * FHID);
    }

    float* outp = (float*)d_out;
    for (int e = 0; e < 2; ++e) {
        float* p_out = outp + (size_t)e * NG * FPROJ;
        float* z_out = outp + (size_t)(2 + e) * NG * FPROJ;
        float* st1 = stats, *st2 = stats + 512;
        hipMemsetAsync(stats, 0, 4 * 256 * 4, stream);
        // t1 = pooled @ Wp1 + bp1 (raw) ; accumulate BN1 stats
        k_mlp<<<64, 256, 0, stream>>>(pooled + (size_t)e * NG * FHID, Wp1, bp1, t1,
                                      128, 256, 0, st1, nullptr, nullptr, nullptr);
        // t2 = relu(BN1(t1)) @ Wp2 + bp2 (raw) ; accumulate BN2 stats
        k_mlp<<<64, 256, 0, stream>>>(t1, Wp2, bp2, t2,
                                      256, 256, 0, st2, st1, g1, be1);
        // z = BN2(t2)
        k_bnapply<<<512, 256, 0, stream>>>(t2, st2, g2, be2, z_out, 256, 0);
        // predictor
        k_mlp<<<64, 128, 0, stream>>>(z_out, Wq1, bq1, t3,
                                      256, 128, 1, nullptr, nullptr, nullptr, nullptr);
        k_mlp<<<64, 256, 0, stream>>>(t3, Wq2, bq2, p_out,
                                      128, 256, 0, nullptr, nullptr, nullptr, nullptr);
    }
}

// Round 7
// 874.926 us; speedup vs baseline: 1.5867x; 1.0310x over previous
//
#include <hip/hip_runtime.h>
#include <hip/hip_bf16.h>

#define NN     50000
#define NEDGE  1600000
#define NG     512
#define FIN    128
#define FHID   128
#define FPROJ  256

// radix CSR build params
#define NBUCK  782            // ceil(50000/64) buckets of 64 nodes (dst>>6)
#define EPB    8192           // edges per A-phase block
#define NABLK  196            // ceil(NEDGE/EPB)
#define NHIST  (NBUCK*NABLK)  // 153,272

typedef __attribute__((ext_vector_type(8))) short short8;
typedef __attribute__((ext_vector_type(4))) float f32x4;

static __device__ __forceinline__ short f2bf(float f) {
    union { float f; unsigned u; } x; x.f = f;
    unsigned r = (x.u + 0x7FFFu + ((x.u >> 16) & 1u)) >> 16;
    return (short)(r & 0xFFFFu);
}
static __device__ __forceinline__ float bf2f(unsigned short u) {
    union { unsigned u; float f; } x; x.u = ((unsigned)u) << 16;
    return x.f;
}
static __device__ __forceinline__ float bflo(unsigned u) {
    union { unsigned u; float f; } x; x.u = u << 16; return x.f;
}
static __device__ __forceinline__ float bfhi(unsigned u) {
    union { unsigned u; float f; } x; x.u = u & 0xFFFF0000u; return x.f;
}
static __device__ __forceinline__ unsigned packbf(float a, float b) {
    return (unsigned)(unsigned short)f2bf(a) | ((unsigned)(unsigned short)f2bf(b) << 16);
}

// ---------------- CSR build (atomic-free at device scope) ----------------

__global__ __launch_bounds__(1024) void k_bhist(const int* __restrict__ dst,
                                                int* __restrict__ histG,
                                                unsigned short* __restrict__ lrank) {
    __shared__ int h[NBUCK];
    for (int j = threadIdx.x; j < NBUCK; j += 1024) h[j] = 0;
    __syncthreads();
    int base = blockIdx.x * EPB;
    for (int t = threadIdx.x; t < EPB; t += 1024) {
        int i = base + t;
        if (i < NEDGE)
            lrank[i] = (unsigned short)atomicAdd(&h[dst[i] >> 6], 1);
    }
    __syncthreads();
    for (int j = threadIdx.x; j < NBUCK; j += 1024)
        histG[j * NABLK + blockIdx.x] = h[j];
}

__global__ void s_scan256(const int* __restrict__ in, int* __restrict__ out,
                          int* __restrict__ bsum, int n) {
    __shared__ int s[256];
    int i = blockIdx.x * 256 + threadIdx.x;
    int v = (i < n) ? in[i] : 0;
    s[threadIdx.x] = v;
    for (int o = 1; o < 256; o <<= 1) {
        __syncthreads();
        int t = (threadIdx.x >= o) ? s[threadIdx.x - o] : 0;
        __syncthreads();
        s[threadIdx.x] += t;
    }
    __syncthreads();
    if (i < n) out[i] = s[threadIdx.x] - v;   // exclusive
    if (threadIdx.x == 255 && bsum) bsum[blockIdx.x] = s[255];
}

__global__ void s_add(int* __restrict__ out, const int* __restrict__ bs, int n) {
    int i = blockIdx.x * 256 + threadIdx.x;
    if (i < n) out[i] += bs[blockIdx.x];
}

__global__ __launch_bounds__(1024) void k_part(const int* __restrict__ src,
                                               const int* __restrict__ dst,
                                               const unsigned short* __restrict__ lrank,
                                               const int* __restrict__ histS,
                                               unsigned* __restrict__ pedge) {
    int base = blockIdx.x * EPB;
    for (int t = threadIdx.x; t < EPB; t += 1024) {
        int i = base + t;
        if (i < NEDGE) {
            int d = dst[i];
            int pos = histS[(d >> 6) * NABLK + blockIdx.x] + (int)lrank[i];
            pedge[pos] = (unsigned)src[i] | ((unsigned)(d & 63) << 16);
        }
    }
}

// one block per 64-node bucket -> fine CSR (ushort srcs) + csroff + dinv
__global__ __launch_bounds__(256) void k_csr(const unsigned* __restrict__ pedge,
                                             const int* __restrict__ histS,
                                             int* __restrict__ csroff,
                                             unsigned short* __restrict__ csrc,
                                             float* __restrict__ dinv) {
    __shared__ int cnt[64], off[64], cur[64];
    int k = blockIdx.x;
    int beg = histS[k * NABLK];
    int end = (k == NBUCK - 1) ? NEDGE : histS[(k + 1) * NABLK];
    if (threadIdx.x < 64) { cnt[threadIdx.x] = 0; cur[threadIdx.x] = 0; }
    __syncthreads();
    for (int e = beg + threadIdx.x; e < end; e += 256)
        atomicAdd(&cnt[pedge[e] >> 16], 1);
    __syncthreads();
    if (threadIdx.x == 0) {
        int s = 0;
        for (int j = 0; j < 64; ++j) { off[j] = s; s += cnt[j]; }
    }
    __syncthreads();
    for (int e = beg + threadIdx.x; e < end; e += 256) {
        unsigned v = pedge[e];
        int j = v >> 16;
        int r = atomicAdd(&cur[j], 1);
        csrc[beg + off[j] + r] = (unsigned short)(v & 0xFFFFu);
    }
    if (threadIdx.x < 64) {
        int node = k * 64 + threadIdx.x;
        if (node < NN) {
            csroff[node] = beg + off[threadIdx.x];
            dinv[node] = 1.0f / sqrtf((float)(cnt[threadIdx.x] + 1));
        }
    }
    if (k == NBUCK - 1 && threadIdx.x == 0) csroff[NN] = NEDGE;
}

// ---------------- MFMA GEMM:  hp[i,:] = bf16( (A[i,:] @ W) * dinv[i] ) ----------------

__global__ void k_prepw(const float* __restrict__ W, short* __restrict__ Wf) {
    int nt = blockIdx.x >> 2, kt = blockIdx.x & 3;
    int lane = threadIdx.x;
    int n = nt * 16 + (lane & 15);
    int kbase = kt * 32 + (lane >> 4) * 8;
    short8 v;
#pragma unroll
    for (int j = 0; j < 8; ++j) v[j] = f2bf(W[(kbase + j) * FHID + n]);
    *(short8*)(Wf + (size_t)((nt * 4 + kt) * 64 + lane) * 8) = v;
}

__global__ __launch_bounds__(256) void k_gemm(const float* __restrict__ Afp,
                                              const unsigned short* __restrict__ Abf,
                                              const short* __restrict__ Wf,
                                              const float* __restrict__ dinv,
                                              unsigned short* __restrict__ hp) {
    int lane = threadIdx.x & 63;
    int wv = threadIdx.x >> 6;
    int quad = lane >> 4;
    int rowbase = blockIdx.x * 64 + wv * 16;
    int arow = rowbase + (lane & 15);
    if (arow >= NN) arow = NN - 1;

    f32x4 acc[8];
#pragma unroll
    for (int i = 0; i < 8; ++i) acc[i] = (f32x4){0.f, 0.f, 0.f, 0.f};

#pragma unroll
    for (int kt = 0; kt < 4; ++kt) {
        short8 af;
        if (Abf) {
            af = *(const short8*)(Abf + (size_t)arow * FIN + kt * 32 + quad * 8);
        } else {
            const float* ap = Afp + (size_t)arow * FIN + kt * 32 + quad * 8;
            float4 a0 = *(const float4*)ap;
            float4 a1 = *(const float4*)(ap + 4);
            af[0] = f2bf(a0.x); af[1] = f2bf(a0.y); af[2] = f2bf(a0.z); af[3] = f2bf(a0.w);
            af[4] = f2bf(a1.x); af[5] = f2bf(a1.y); af[6] = f2bf(a1.z); af[7] = f2bf(a1.w);
        }
#pragma unroll
        for (int nt = 0; nt < 8; ++nt) {
            short8 bf = *(const short8*)(Wf + (size_t)((nt * 4 + kt) * 64 + lane) * 8);
            acc[nt] = __builtin_amdgcn_mfma_f32_16x16x32_bf16(af, bf, acc[nt], 0, 0, 0);
        }
    }
    // C/D layout: col = lane&15, row = quad*4 + reg   [measured m89/m91]
    float4 dv = *(const float4*)(dinv + rowbase + quad * 4);
    float dvv[4] = {dv.x, dv.y, dv.z, dv.w};
    int col = lane & 15;
#pragma unroll
    for (int r = 0; r < 4; ++r) {
        int orow = rowbase + quad * 4 + r;
        if (orow < NN) {
#pragma unroll
            for (int nt = 0; nt < 8; ++nt)
                hp[(size_t)orow * FHID + nt * 16 + col] =
                    (unsigned short)f2bf(acc[nt][r] * dvv[r]);
        }
    }
}

// ------- Aggregate full 128-feature row, single pass, deep unroll (16 in flight)

__global__ __launch_bounds__(256) void k_agg(const uint2* __restrict__ hp,
                                             const int* __restrict__ off,
                                             const unsigned short* __restrict__ csrc,
                                             const float* __restrict__ dinv,
                                             const float* __restrict__ bias,
                                             const unsigned short* __restrict__ resid,
                                             unsigned short* __restrict__ hout) {
    int tid = threadIdx.x;
    int l2 = tid & 31;                        // 4 feats per lane -> 128 feats
    int node = blockIdx.x * 8 + (tid >> 5);   // 6250 blocks * 8 = 50000 exactly
    int beg = off[node], end = off[node + 1];

    uint2 sv = hp[(size_t)node * 32 + l2];
    float a0 = bflo(sv.x), a1 = bfhi(sv.x), a2 = bflo(sv.y), a3 = bfhi(sv.y);

    int e = beg;
    for (; e + 16 <= end; e += 16) {
        int s[16];
#pragma unroll
        for (int j = 0; j < 16; ++j) s[j] = (int)csrc[e + j];
        uint2 v[16];
#pragma unroll
        for (int j = 0; j < 16; ++j) v[j] = hp[(size_t)s[j] * 32 + l2];
#pragma unroll
        for (int j = 0; j < 16; ++j) {
            a0 += bflo(v[j].x); a1 += bfhi(v[j].x);
            a2 += bflo(v[j].y); a3 += bfhi(v[j].y);
        }
    }
    for (; e + 4 <= end; e += 4) {
        int s[4];
#pragma unroll
        for (int j = 0; j < 4; ++j) s[j] = (int)csrc[e + j];
        uint2 v[4];
#pragma unroll
        for (int j = 0; j < 4; ++j) v[j] = hp[(size_t)s[j] * 32 + l2];
#pragma unroll
        for (int j = 0; j < 4; ++j) {
            a0 += bflo(v[j].x); a1 += bfhi(v[j].x);
            a2 += bflo(v[j].y); a3 += bfhi(v[j].y);
        }
    }
    for (; e < end; ++e) {
        uint2 v = hp[(size_t)csrc[e] * 32 + l2];
        a0 += bflo(v.x); a1 += bfhi(v.x);
        a2 += bflo(v.y); a3 += bfhi(v.y);
    }
    float dv = dinv[node];
    float4 b = ((const float4*)bias)[l2];
    float o0 = fmaxf(a0 * dv + b.x, 0.f);
    float o1 = fmaxf(a1 * dv + b.y, 0.f);
    float o2 = fmaxf(a2 * dv + b.z, 0.f);
    float o3 = fmaxf(a3 * dv + b.w, 0.f);
    if (resid) {
        uint2 rv = ((const uint2*)resid)[(size_t)node * 32 + l2];
        o0 += bflo(rv.x); o1 += bfhi(rv.x);
        o2 += bflo(rv.y); o3 += bfhi(rv.y);
    }
    uint2 ov;
    ov.x = packbf(o0, o1);
    ov.y = packbf(o2, o3);
    ((uint2*)hout)[(size_t)node * 32 + l2] = ov;
}

// ---------------- Pooling ----------------

__global__ void k_starts(const int* __restrict__ batch, int* __restrict__ starts) {
    int i = blockIdx.x * 256 + threadIdx.x;
    if (i >= NN) return;
    int b = batch[i];
    if (i == 0) {
        for (int g = 0; g <= b; ++g) starts[g] = 0;
    } else {
        int p = batch[i - 1];
        for (int g = p + 1; g <= b; ++g) starts[g] = i;
    }
    if (i == NN - 1) {
        for (int g = b + 1; g <= NG; ++g) starts[g] = NN;
    }
}

__global__ void k_pool(const unsigned short* __restrict__ h, const int* __restrict__ starts,
                       float* __restrict__ pooled) {
    int g = blockIdx.x, c = threadIdx.x;   // 128 threads
    int beg = starts[g], end = starts[g + 1];
    float s = 0.f;
    for (int i = beg; i < end; ++i) s += bf2f(h[(size_t)i * FHID + c]);
    int cnt = end - beg;
    pooled[g * FHID + c] = s / (float)(cnt > 0 ? cnt : 1);
}

// ---------------- Fused MLP / BN heads (M = 512 rows) ----------------

__global__ void k_mlp(const float* __restrict__ A, const float* __restrict__ W,
                      const float* __restrict__ bias, float* __restrict__ out,
                      int K, int Nc, int act,
                      float* __restrict__ statsOut,
                      const float* __restrict__ statsIn,
                      const float* __restrict__ gIn, const float* __restrict__ beIn) {
    __shared__ float As[8 * 256];
    __shared__ float scl[256], shf[256];
    int n = threadIdx.x;                 // blockDim.x == Nc
    int r0 = blockIdx.x * 8;
    if (statsIn && n < K) {
        float m = statsIn[n] * (1.f / 512.f);
        float var = statsIn[K + n] * (1.f / 512.f) - m * m;
        float inv = 1.0f / sqrtf(var + 1e-5f);
        float s = gIn[n] * inv;
        scl[n] = s;
        shf[n] = beIn[n] - m * s;
    }
    __syncthreads();
    for (int idx = n; idx < 8 * K; idx += blockDim.x) {
        float v = A[(size_t)r0 * K + idx];
        if (statsIn) {
            int k = idx & (K - 1);       // K is 128 or 256
            v = fmaxf(v * scl[k] + shf[k], 0.f);   // relu(BN(.)) input transform
        }
        As[idx] = v;
    }
    __syncthreads();
    float bb = bias[n];
    float acc[8];
#pragma unroll
    for (int r = 0; r < 8; ++r) acc[r] = bb;
    for (int k = 0; k < K; ++k) {
        float w = W[(size_t)k * Nc + n];
#pragma unroll
        for (int r = 0; r < 8; ++r) acc[r] = fmaf(As[r * K + k], w, acc[r]);
    }
    if (statsOut) {
        float s = 0.f, q = 0.f;
#pragma unroll
        for (int r = 0; r < 8; ++r) { s += acc[r]; q += acc[r] * acc[r]; }
        atomicAdd(&statsOut[n], s);
        atomicAdd(&statsOut[Nc + n], q);
    }
#pragma unroll
    for (int r = 0; r < 8; ++r) {
        float v = acc[r];
        if (act) v = fmaxf(v, 0.f);
        out[(size_t)(r0 + r) * Nc + n] = v;
    }
}

__global__ void k_bnapply(const float* __restrict__ X, const float* __restrict__ stats,
                          const float* __restrict__ gamma, const float* __restrict__ beta,
                          float* __restrict__ out, int Nc, int act) {
    int i = blockIdx.x * 256 + threadIdx.x;
    if (i >= 512 * Nc) return;
    int c = i % Nc;
    float m = stats[c] * (1.f / 512.f);
    float var = stats[Nc + c] * (1.f / 512.f) - m * m;
    float inv = 1.0f / sqrtf(var + 1e-5f);
    float v = gamma[c] * (X[i] - m) * inv + beta[c];
    if (act) v = fmaxf(v, 0.f);
    out[i] = v;
}

// ---------------- Orchestration ----------------

extern "C" void kernel_launch(void* const* d_in, const int* in_sizes, int n_in,
                              void* d_out, int out_size, void* d_ws, size_t ws_size,
                              hipStream_t stream) {
    const float* x[2]     = {(const float*)d_in[0], (const float*)d_in[3]};
    const int*   ei[2]    = {(const int*)d_in[1], (const int*)d_in[4]};
    const int*   batch[2] = {(const int*)d_in[2], (const int*)d_in[5]};
    const float* W[3]  = {(const float*)d_in[6], (const float*)d_in[8], (const float*)d_in[10]};
    const float* bb[3] = {(const float*)d_in[7], (const float*)d_in[9], (const float*)d_in[11]};
    const float* Wp1 = (const float*)d_in[12]; const float* bp1 = (const float*)d_in[13];
    const float* g1  = (const float*)d_in[14]; const float* be1 = (const float*)d_in[15];
    const float* Wp2 = (const float*)d_in[16]; const float* bp2 = (const float*)d_in[17];
    const float* g2  = (const float*)d_in[18]; const float* be2 = (const float*)d_in[19];
    const float* Wq1 = (const float*)d_in[20]; const float* bq1 = (const float*)d_in[21];
    const float* Wq2 = (const float*)d_in[22]; const float* bq2 = (const float*)d_in[23];

    char* ws = (char*)d_ws;
    size_t off = 0;
    auto alloc = [&](size_t bytes) -> void* {
        void* p = ws + off;
        off += (bytes + 255) & ~(size_t)255;
        return p;
    };
    unsigned short* h_cur  = (unsigned short*)alloc((size_t)NN * FHID * 2);  // bf16 state
    unsigned short* hp     = (unsigned short*)alloc((size_t)NN * FHID * 2);  // bf16 pre-agg
    unsigned short* csrc   = (unsigned short*)alloc((size_t)NEDGE * 2);
    int*            csroff = (int*)alloc((size_t)(NN + 1) * 4);
    unsigned short* lrank  = (unsigned short*)alloc((size_t)NEDGE * 2);
    unsigned*       pedge  = (unsigned*)alloc((size_t)NEDGE * 4);
    int*            histG  = (int*)alloc((size_t)NHIST * 4);
    int*            histS  = (int*)alloc((size_t)NHIST * 4);
    int*            bsum1  = (int*)alloc(1024 * 4);
    int*            bsum1s = (int*)alloc(1024 * 4);
    int*            bsum2  = (int*)alloc(256 * 4);
    int*            bsum2s = (int*)alloc(256 * 4);
    float*          dinv   = (float*)alloc((size_t)50048 * 4);   // padded for gemm epilogue
    int*            starts = (int*)alloc((NG + 1) * 4);
    float*          pooled = (float*)alloc((size_t)2 * NG * FHID * 4);
    short*          Wf     = (short*)alloc((size_t)3 * 16384 * 2);
    float*          t1     = (float*)alloc((size_t)512 * 256 * 4);
    float*          t2     = (float*)alloc((size_t)512 * 256 * 4);
    float*          t3     = (float*)alloc((size_t)512 * 128 * 4);
    float*          stats  = (float*)alloc(4 * 256 * 4);  // [BN1: 256s+256q][BN2: 256s+256q]

    for (int l = 0; l < 3; ++l)
        k_prepw<<<32, 64, 0, stream>>>(W[l], Wf + (size_t)l * 16384);

    const int nsb1 = (NHIST + 255) / 256;          // 599 scan blocks
    const int nsb2 = (nsb1 + 255) / 256;           // 3

    for (int e = 0; e < 2; ++e) {
        const int* src = ei[e];
        const int* dst = ei[e] + NEDGE;
        // atomic-free radix CSR build
        k_bhist<<<NABLK, 1024, 0, stream>>>(dst, histG, lrank);
        s_scan256<<<nsb1, 256, 0, stream>>>(histG, histS, bsum1, NHIST);
        s_scan256<<<nsb2, 256, 0, stream>>>(bsum1, bsum1s, bsum2, nsb1);
        s_scan256<<<1, 256, 0, stream>>>(bsum2, bsum2s, nullptr, nsb2);
        s_add<<<nsb2, 256, 0, stream>>>(bsum1s, bsum2s, nsb1);
        s_add<<<nsb1, 256, 0, stream>>>(histS, bsum1s, NHIST);
        k_part<<<NABLK, 1024, 0, stream>>>(src, dst, lrank, histS, pedge);
        k_csr<<<NBUCK, 256, 0, stream>>>(pedge, histS, csroff, csrc, dinv);

        for (int l = 0; l < 3; ++l) {
            const float* Afp = (l == 0) ? x[e] : nullptr;
            const unsigned short* Abf = (l == 0) ? nullptr : h_cur;
            const unsigned short* resid = (l == 0) ? nullptr : h_cur;
            k_gemm<<<782, 256, 0, stream>>>(Afp, Abf, Wf + (size_t)l * 16384, dinv, hp);
            k_agg<<<6250, 256, 0, stream>>>((const uint2*)hp, csroff, csrc, dinv,
                                            bb[l], resid, h_cur);
        }
        k_starts<<<196, 256, 0, stream>>>(batch[e], starts);
        k_pool<<<NG, 128, 0, stream>>>(h_cur, starts, pooled + (size_t)e * NG * FHID);
    }

    float* outp = (float*)d_out;
    for (int e = 0; e < 2; ++e) {
        float* p_out = outp + (size_t)e * NG * FPROJ;
        float* z_out = outp + (size_t)(2 + e) * NG * FPROJ;
        float* st1 = stats, *st2 = stats + 512;
        hipMemsetAsync(stats, 0, 4 * 256 * 4, stream);
        // t1 = pooled @ Wp1 + bp1 (raw) ; accumulate BN1 stats
        k_mlp<<<64, 256, 0, stream>>>(pooled + (size_t)e * NG * FHID, Wp1, bp1, t1,
                                      128, 256, 0, st1, nullptr, nullptr, nullptr);
        // t2 = relu(BN1(t1)) @ Wp2 + bp2 (raw) ; accumulate BN2 stats
        k_mlp<<<64, 256, 0, stream>>>(t1, Wp2, bp2, t2,
                                      256, 256, 0, st2, st1, g1, be1);
        // z = BN2(t2)
        k_bnapply<<<512, 256, 0, stream>>>(t2, st2, g2, be2, z_out, 256, 0);
        // predictor
        k_mlp<<<64, 128, 0, stream>>>(z_out, Wq1, bq1, t3,
                                      256, 128, 1, nullptr, nullptr, nullptr, nullptr);
        k_mlp<<<64, 256, 0, stream>>>(t3, Wq2, bq2, p_out,
                                      128, 256, 0, nullptr, nullptr, nullptr, nullptr);
    }
}

// Round 8
// 773.003 us; speedup vs baseline: 1.7960x; 1.1319x over previous
//
#include <hip/hip_runtime.h>
#include <hip/hip_bf16.h>

#define NN     50000
#define NN2    100000
#define NEDGE  1600000
#define NE2    3200000
#define NG     512
#define FIN    128
#define FHID   128
#define FPROJ  256

// merged radix CSR build params
#define NBUCK  782            // per-graph buckets of 64 nodes
#define NBUCK2 1564
#define EPB    8192
#define NABLK  196            // per-graph A-blocks
#define NABLK2 392
#define NHIST2 (NBUCK2*NABLK2)   // 613,088

typedef __attribute__((ext_vector_type(8))) short short8;
typedef __attribute__((ext_vector_type(4))) float f32x4;

static __device__ __forceinline__ short f2bf(float f) {
    union { float f; unsigned u; } x; x.f = f;
    unsigned r = (x.u + 0x7FFFu + ((x.u >> 16) & 1u)) >> 16;
    return (short)(r & 0xFFFFu);
}
static __device__ __forceinline__ float bf2f(unsigned short u) {
    union { unsigned u; float f; } x; x.u = ((unsigned)u) << 16;
    return x.f;
}
static __device__ __forceinline__ float bflo(unsigned u) {
    union { unsigned u; float f; } x; x.u = u << 16; return x.f;
}
static __device__ __forceinline__ float bfhi(unsigned u) {
    union { unsigned u; float f; } x; x.u = u & 0xFFFF0000u; return x.f;
}
static __device__ __forceinline__ unsigned packbf(float a, float b) {
    return (unsigned)(unsigned short)f2bf(a) | ((unsigned)(unsigned short)f2bf(b) << 16);
}

// ---------------- merged CSR build (both graphs, atomic-free at device scope) ----

__global__ __launch_bounds__(1024) void k_bhist(const int* __restrict__ dst0,
                                                const int* __restrict__ dst1,
                                                int* __restrict__ histG,
                                                unsigned short* __restrict__ lrank) {
    __shared__ int h[NBUCK2];
    for (int j = threadIdx.x; j < NBUCK2; j += 1024) h[j] = 0;
    __syncthreads();
    int b = blockIdx.x;                  // 0..391
    int g = b / NABLK, blk = b % NABLK;
    const int* dst = g ? dst1 : dst0;
    int base = blk * EPB;
    int gb = g * NBUCK;
    for (int t = threadIdx.x; t < EPB; t += 1024) {
        int i = base + t;
        if (i < NEDGE)
            lrank[(size_t)g * NEDGE + i] =
                (unsigned short)atomicAdd(&h[gb + (dst[i] >> 6)], 1);
    }
    __syncthreads();
    for (int j = threadIdx.x; j < NBUCK2; j += 1024)
        histG[(size_t)j * NABLK2 + b] = h[j];
}

__global__ void s_scan256(const int* __restrict__ in, int* __restrict__ out,
                          int* __restrict__ bsum, int n) {
    __shared__ int s[256];
    int i = blockIdx.x * 256 + threadIdx.x;
    int v = (i < n) ? in[i] : 0;
    s[threadIdx.x] = v;
    for (int o = 1; o < 256; o <<= 1) {
        __syncthreads();
        int t = (threadIdx.x >= o) ? s[threadIdx.x - o] : 0;
        __syncthreads();
        s[threadIdx.x] += t;
    }
    __syncthreads();
    if (i < n) out[i] = s[threadIdx.x] - v;   // exclusive
    if (threadIdx.x == 255 && bsum) bsum[blockIdx.x] = s[255];
}

__global__ void s_add(int* __restrict__ out, const int* __restrict__ bs, int n) {
    int i = blockIdx.x * 256 + threadIdx.x;
    if (i < n) out[i] += bs[blockIdx.x];
}

__global__ __launch_bounds__(1024) void k_part(const int* __restrict__ src0,
                                               const int* __restrict__ dst0,
                                               const int* __restrict__ src1,
                                               const int* __restrict__ dst1,
                                               const unsigned short* __restrict__ lrank,
                                               const int* __restrict__ histS,
                                               unsigned* __restrict__ pedge) {
    int b = blockIdx.x;
    int g = b / NABLK, blk = b % NABLK;
    const int* src = g ? src1 : src0;
    const int* dst = g ? dst1 : dst0;
    int base = blk * EPB;
    int gb = g * NBUCK;
    for (int t = threadIdx.x; t < EPB; t += 1024) {
        int i = base + t;
        if (i < NEDGE) {
            int d = dst[i];
            int pos = histS[(size_t)(gb + (d >> 6)) * NABLK2 + b]
                      + (int)lrank[(size_t)g * NEDGE + i];
            pedge[pos] = (unsigned)src[i] | ((unsigned)(d & 63) << 16);
        }
    }
}

// one block per 64-node bucket -> fine CSR (ushort local srcs) + csroff + dinv
__global__ __launch_bounds__(256) void k_csr(const unsigned* __restrict__ pedge,
                                             const int* __restrict__ histS,
                                             int* __restrict__ csroff,
                                             unsigned short* __restrict__ csrc,
                                             float* __restrict__ dinv) {
    __shared__ int cnt[64], off[64], cur[64];
    int k = blockIdx.x;                  // 0..1563
    int g = k / NBUCK;
    int nl0 = (k - g * NBUCK) * 64;      // local node base
    int beg = histS[(size_t)k * NABLK2];
    int end = (k == NBUCK2 - 1) ? NE2 : histS[(size_t)(k + 1) * NABLK2];
    if (threadIdx.x < 64) { cnt[threadIdx.x] = 0; cur[threadIdx.x] = 0; }
    __syncthreads();
    for (int e = beg + threadIdx.x; e < end; e += 256)
        atomicAdd(&cnt[pedge[e] >> 16], 1);
    __syncthreads();
    if (threadIdx.x == 0) {
        int s = 0;
        for (int j = 0; j < 64; ++j) { off[j] = s; s += cnt[j]; }
    }
    __syncthreads();
    for (int e = beg + threadIdx.x; e < end; e += 256) {
        unsigned v = pedge[e];
        int j = v >> 16;
        int r = atomicAdd(&cur[j], 1);
        csrc[beg + off[j] + r] = (unsigned short)(v & 0xFFFFu);
    }
    if (threadIdx.x < 64) {
        int nl = nl0 + threadIdx.x;
        if (nl < NN) {
            int gn = g * NN + nl;
            csroff[gn] = beg + off[threadIdx.x];
            dinv[gn] = 1.0f / sqrtf((float)(cnt[threadIdx.x] + 1));
        }
    }
    if (k == NBUCK2 - 1 && threadIdx.x == 0) csroff[NN2] = NE2;
}

// ---------------- MFMA GEMM over both graphs: hp[i,:] = bf16((A[i,:]@W)*dinv[i]) ----

__global__ void k_prepw(const float* __restrict__ W0, const float* __restrict__ W1,
                        const float* __restrict__ W2, short* __restrict__ Wf) {
    int b = blockIdx.x;                  // 96 blocks
    int l = b >> 5; b &= 31;
    const float* W = (l == 0) ? W0 : (l == 1) ? W1 : W2;
    int nt = b >> 2, kt = b & 3;
    int lane = threadIdx.x;
    int n = nt * 16 + (lane & 15);
    int kbase = kt * 32 + (lane >> 4) * 8;
    short8 v;
#pragma unroll
    for (int j = 0; j < 8; ++j) v[j] = f2bf(W[(kbase + j) * FHID + n]);
    *(short8*)(Wf + (size_t)l * 16384 + (size_t)((nt * 4 + kt) * 64 + lane) * 8) = v;
}

__global__ __launch_bounds__(256) void k_gemm(const float* __restrict__ x1,
                                              const float* __restrict__ x2,
                                              const unsigned short* __restrict__ Abf,
                                              const short* __restrict__ Wf,
                                              const float* __restrict__ dinv,
                                              unsigned short* __restrict__ hp) {
    int lane = threadIdx.x & 63;
    int wv = threadIdx.x >> 6;
    int quad = lane >> 4;
    int rowbase = blockIdx.x * 64 + wv * 16;    // 1564 blocks -> 100,096 rows
    int arow = rowbase + (lane & 15);
    if (arow >= NN2) arow = NN2 - 1;

    f32x4 acc[8];
#pragma unroll
    for (int i = 0; i < 8; ++i) acc[i] = (f32x4){0.f, 0.f, 0.f, 0.f};

#pragma unroll
    for (int kt = 0; kt < 4; ++kt) {
        short8 af;
        if (Abf) {
            af = *(const short8*)(Abf + (size_t)arow * FIN + kt * 32 + quad * 8);
        } else {
            const float* ap = (arow < NN ? x1 + (size_t)arow * FIN
                                         : x2 + (size_t)(arow - NN) * FIN)
                              + kt * 32 + quad * 8;
            float4 a0 = *(const float4*)ap;
            float4 a1 = *(const float4*)(ap + 4);
            af[0] = f2bf(a0.x); af[1] = f2bf(a0.y); af[2] = f2bf(a0.z); af[3] = f2bf(a0.w);
            af[4] = f2bf(a1.x); af[5] = f2bf(a1.y); af[6] = f2bf(a1.z); af[7] = f2bf(a1.w);
        }
#pragma unroll
        for (int nt = 0; nt < 8; ++nt) {
            short8 bf = *(const short8*)(Wf + (size_t)((nt * 4 + kt) * 64 + lane) * 8);
            acc[nt] = __builtin_amdgcn_mfma_f32_16x16x32_bf16(af, bf, acc[nt], 0, 0, 0);
        }
    }
    // C/D layout: col = lane&15, row = quad*4 + reg   [measured m89/m91]
    float4 dv = *(const float4*)(dinv + rowbase + quad * 4);
    float dvv[4] = {dv.x, dv.y, dv.z, dv.w};
    int col = lane & 15;
#pragma unroll
    for (int r = 0; r < 4; ++r) {
        int orow = rowbase + quad * 4 + r;
        if (orow < NN2) {
#pragma unroll
            for (int nt = 0; nt < 8; ++nt)
                hp[(size_t)orow * FHID + nt * 16 + col] =
                    (unsigned short)f2bf(acc[nt][r] * dvv[r]);
        }
    }
}

// ------- Aggregate full 128-feature row, per graph (pointers pre-offset host-side)

__global__ __launch_bounds__(256) void k_agg(const uint2* __restrict__ hp,
                                             const int* __restrict__ off,
                                             const unsigned short* __restrict__ csrc,
                                             const float* __restrict__ dinv,
                                             const float* __restrict__ bias,
                                             const unsigned short* __restrict__ resid,
                                             unsigned short* __restrict__ hout) {
    int tid = threadIdx.x;
    int l2 = tid & 31;                        // 4 feats per lane -> 128 feats
    int node = blockIdx.x * 8 + (tid >> 5);   // 6250 blocks * 8 = 50000 exactly
    int beg = off[node], end = off[node + 1];

    uint2 sv = hp[(size_t)node * 32 + l2];
    float a0 = bflo(sv.x), a1 = bfhi(sv.x), a2 = bflo(sv.y), a3 = bfhi(sv.y);

    int e = beg;
    for (; e + 16 <= end; e += 16) {
        int s[16];
#pragma unroll
        for (int j = 0; j < 16; ++j) s[j] = (int)csrc[e + j];
        uint2 v[16];
#pragma unroll
        for (int j = 0; j < 16; ++j) v[j] = hp[(size_t)s[j] * 32 + l2];
#pragma unroll
        for (int j = 0; j < 16; ++j) {
            a0 += bflo(v[j].x); a1 += bfhi(v[j].x);
            a2 += bflo(v[j].y); a3 += bfhi(v[j].y);
        }
    }
    for (; e + 4 <= end; e += 4) {
        int s[4];
#pragma unroll
        for (int j = 0; j < 4; ++j) s[j] = (int)csrc[e + j];
        uint2 v[4];
#pragma unroll
        for (int j = 0; j < 4; ++j) v[j] = hp[(size_t)s[j] * 32 + l2];
#pragma unroll
        for (int j = 0; j < 4; ++j) {
            a0 += bflo(v[j].x); a1 += bfhi(v[j].x);
            a2 += bflo(v[j].y); a3 += bfhi(v[j].y);
        }
    }
    for (; e < end; ++e) {
        uint2 v = hp[(size_t)csrc[e] * 32 + l2];
        a0 += bflo(v.x); a1 += bfhi(v.x);
        a2 += bflo(v.y); a3 += bfhi(v.y);
    }
    float dv = dinv[node];
    float4 b = ((const float4*)bias)[l2];
    float o0 = fmaxf(a0 * dv + b.x, 0.f);
    float o1 = fmaxf(a1 * dv + b.y, 0.f);
    float o2 = fmaxf(a2 * dv + b.z, 0.f);
    float o3 = fmaxf(a3 * dv + b.w, 0.f);
    if (resid) {
        uint2 rv = ((const uint2*)resid)[(size_t)node * 32 + l2];
        o0 += bflo(rv.x); o1 += bfhi(rv.x);
        o2 += bflo(rv.y); o3 += bfhi(rv.y);
    }
    uint2 ov;
    ov.x = packbf(o0, o1);
    ov.y = packbf(o2, o3);
    ((uint2*)hout)[(size_t)node * 32 + l2] = ov;
}

// ---------------- Pooling (both graphs) ----------------

__global__ void k_starts(const int* __restrict__ b0, const int* __restrict__ b1,
                         int* __restrict__ starts) {
    int blk = blockIdx.x;                 // 392 blocks
    int g = blk / NABLK;
    int i = (blk - g * NABLK) * 256 + threadIdx.x;
    if (i >= NN) return;
    const int* batch = g ? b1 : b0;
    int* st = starts + g * (NG + 1);
    int b = batch[i];
    if (i == 0) {
        for (int q = 0; q <= b; ++q) st[q] = 0;
    } else {
        int p = batch[i - 1];
        for (int q = p + 1; q <= b; ++q) st[q] = i;
    }
    if (i == NN - 1) {
        for (int q = b + 1; q <= NG; ++q) st[q] = NN;
    }
}

__global__ void k_pool(const unsigned short* __restrict__ h, const int* __restrict__ starts,
                       float* __restrict__ pooled) {
    int b = blockIdx.x;                  // 1024 blocks
    int g = b >> 9, lg = b & 511;
    int c = threadIdx.x;                 // 128 threads
    const int* st = starts + g * (NG + 1);
    const unsigned short* hb = h + (size_t)g * NN * FHID;
    int beg = st[lg], end = st[lg + 1];
    float s = 0.f;
    for (int i = beg; i < end; ++i) s += bf2f(hb[(size_t)i * FHID + c]);
    int cnt = end - beg;
    pooled[(size_t)b * FHID + c] = s / (float)(cnt > 0 ? cnt : 1);
}

// ---------------- Fused MLP / BN heads (1024 rows = both graphs) ----------------
// per-graph BN stats: blocks 0-63 graph0, 64-127 graph1; stats base += g*512

__global__ void k_mlp(const float* __restrict__ A, const float* __restrict__ W,
                      const float* __restrict__ bias, float* __restrict__ out,
                      int K, int Nc, int act,
                      float* __restrict__ statsOut,
                      const float* __restrict__ statsIn,
                      const float* __restrict__ gIn, const float* __restrict__ beIn) {
    __shared__ float As[8 * 256];
    __shared__ float scl[256], shf[256];
    int n = threadIdx.x;                 // blockDim.x == Nc
    int r0 = blockIdx.x * 8;             // 128 blocks -> 1024 rows
    int g = blockIdx.x >> 6;
    if (statsIn && n < K) {
        const float* si = statsIn + g * 512;
        float m = si[n] * (1.f / 512.f);
        float var = si[K + n] * (1.f / 512.f) - m * m;
        float inv = 1.0f / sqrtf(var + 1e-5f);
        float s = gIn[n] * inv;
        scl[n] = s;
        shf[n] = beIn[n] - m * s;
    }
    __syncthreads();
    for (int idx = n; idx < 8 * K; idx += blockDim.x) {
        float v = A[(size_t)r0 * K + idx];
        if (statsIn) {
            int k = idx & (K - 1);       // K is 128 or 256
            v = fmaxf(v * scl[k] + shf[k], 0.f);   // relu(BN(.)) input transform
        }
        As[idx] = v;
    }
    __syncthreads();
    float bb = bias[n];
    float acc[8];
#pragma unroll
    for (int r = 0; r < 8; ++r) acc[r] = bb;
    for (int k = 0; k < K; ++k) {
        float w = W[(size_t)k * Nc + n];
#pragma unroll
        for (int r = 0; r < 8; ++r) acc[r] = fmaf(As[r * K + k], w, acc[r]);
    }
    if (statsOut) {
        float s = 0.f, q = 0.f;
#pragma unroll
        for (int r = 0; r < 8; ++r) { s += acc[r]; q += acc[r] * acc[r]; }
        atomicAdd(&statsOut[g * 512 + n], s);
        atomicAdd(&statsOut[g * 512 + Nc + n], q);
    }
#pragma unroll
    for (int r = 0; r < 8; ++r) {
        float v = acc[r];
        if (act) v = fmaxf(v, 0.f);
        out[(size_t)(r0 + r) * Nc + n] = v;
    }
}

__global__ void k_bnapply(const float* __restrict__ X, const float* __restrict__ stats,
                          const float* __restrict__ gamma, const float* __restrict__ beta,
                          float* __restrict__ out, int Nc, int act) {
    int i = blockIdx.x * 256 + threadIdx.x;          // 1024*Nc elements
    if (i >= 1024 * Nc) return;
    int c = i % Nc;
    int g = i / (512 * Nc);
    const float* st = stats + g * 512;
    float m = st[c] * (1.f / 512.f);
    float var = st[Nc + c] * (1.f / 512.f) - m * m;
    float inv = 1.0f / sqrtf(var + 1e-5f);
    float v = gamma[c] * (X[i] - m) * inv + beta[c];
    if (act) v = fmaxf(v, 0.f);
    out[i] = v;
}

// ---------------- Orchestration ----------------

extern "C" void kernel_launch(void* const* d_in, const int* in_sizes, int n_in,
                              void* d_out, int out_size, void* d_ws, size_t ws_size,
                              hipStream_t stream) {
    const float* x1 = (const float*)d_in[0];
    const float* x2 = (const float*)d_in[3];
    const int*   ei[2]    = {(const int*)d_in[1], (const int*)d_in[4]};
    const int*   batch[2] = {(const int*)d_in[2], (const int*)d_in[5]};
    const float* W[3]  = {(const float*)d_in[6], (const float*)d_in[8], (const float*)d_in[10]};
    const float* bb[3] = {(const float*)d_in[7], (const float*)d_in[9], (const float*)d_in[11]};
    const float* Wp1 = (const float*)d_in[12]; const float* bp1 = (const float*)d_in[13];
    const float* g1  = (const float*)d_in[14]; const float* be1 = (const float*)d_in[15];
    const float* Wp2 = (const float*)d_in[16]; const float* bp2 = (const float*)d_in[17];
    const float* g2  = (const float*)d_in[18]; const float* be2 = (const float*)d_in[19];
    const float* Wq1 = (const float*)d_in[20]; const float* bq1 = (const float*)d_in[21];
    const float* Wq2 = (const float*)d_in[22]; const float* bq2 = (const float*)d_in[23];

    char* ws = (char*)d_ws;
    size_t off = 0;
    auto alloc = [&](size_t bytes) -> void* {
        void* p = ws + off;
        off += (bytes + 255) & ~(size_t)255;
        return p;
    };
    unsigned short* h_cur  = (unsigned short*)alloc((size_t)NN2 * FHID * 2);  // bf16 state
    unsigned short* hp     = (unsigned short*)alloc((size_t)NN2 * FHID * 2);  // bf16 pre-agg
    unsigned short* csrc   = (unsigned short*)alloc((size_t)NE2 * 2);
    int*            csroff = (int*)alloc((size_t)(NN2 + 1) * 4);
    unsigned short* lrank  = (unsigned short*)alloc((size_t)NE2 * 2);
    unsigned*       pedge  = (unsigned*)alloc((size_t)NE2 * 4);
    int*            histG  = (int*)alloc((size_t)NHIST2 * 4);
    int*            histS  = (int*)alloc((size_t)NHIST2 * 4);
    int*            bsum1  = (int*)alloc(2560 * 4);
    int*            bsum1s = (int*)alloc(2560 * 4);
    int*            bsum2  = (int*)alloc(256 * 4);
    int*            bsum2s = (int*)alloc(256 * 4);
    float*          dinv   = (float*)alloc((size_t)100352 * 4);  // padded for gemm epilogue
    int*            starts = (int*)alloc(2 * (NG + 1) * 4);
    float*          pooled = (float*)alloc((size_t)2 * NG * FHID * 4);
    short*          Wf     = (short*)alloc((size_t)3 * 16384 * 2);
    float*          t1     = (float*)alloc((size_t)1024 * 256 * 4);
    float*          t2     = (float*)alloc((size_t)1024 * 256 * 4);
    float*          t3     = (float*)alloc((size_t)1024 * 128 * 4);
    float*          stats  = (float*)alloc(2048 * 4);  // [st1: 2g x 512][st2: 2g x 512]

    const int* src0 = ei[0];           const int* dst0 = ei[0] + NEDGE;
    const int* src1 = ei[1];           const int* dst1 = ei[1] + NEDGE;

    k_prepw<<<96, 64, 0, stream>>>(W[0], W[1], W[2], Wf);

    // merged atomic-free radix CSR build (both graphs)
    const int nsb1 = (NHIST2 + 255) / 256;        // 2395
    const int nsb2 = (nsb1 + 255) / 256;          // 10
    k_bhist<<<NABLK2, 1024, 0, stream>>>(dst0, dst1, histG, lrank);
    s_scan256<<<nsb1, 256, 0, stream>>>(histG, histS, bsum1, NHIST2);
    s_scan256<<<nsb2, 256, 0, stream>>>(bsum1, bsum1s, bsum2, nsb1);
    s_scan256<<<1, 256, 0, stream>>>(bsum2, bsum2s, nullptr, nsb2);
    s_add<<<nsb2, 256, 0, stream>>>(bsum1s, bsum2s, nsb1);
    s_add<<<nsb1, 256, 0, stream>>>(histS, bsum1s, NHIST2);
    k_part<<<NABLK2, 1024, 0, stream>>>(src0, dst0, src1, dst1, lrank, histS, pedge);
    k_csr<<<NBUCK2, 256, 0, stream>>>(pedge, histS, csroff, csrc, dinv);

    // encoder: merged gemm, per-graph aggregation
    for (int l = 0; l < 3; ++l) {
        const unsigned short* Abf = (l == 0) ? nullptr : h_cur;
        k_gemm<<<NBUCK2, 256, 0, stream>>>(x1, x2, Abf, Wf + (size_t)l * 16384, dinv, hp);
        for (int g = 0; g < 2; ++g) {
            size_t nb = (size_t)g * NN;
            const unsigned short* resid = (l == 0) ? nullptr : h_cur + nb * FHID;
            k_agg<<<6250, 256, 0, stream>>>((const uint2*)(hp + nb * FHID),
                                            csroff + nb, csrc, dinv + nb,
                                            bb[l], resid, h_cur + nb * FHID);
        }
    }
    k_starts<<<NABLK2, 256, 0, stream>>>(batch[0], batch[1], starts);
    k_pool<<<1024, 128, 0, stream>>>(h_cur, starts, pooled);

    // merged heads (1024 rows, per-graph BN stats)
    float* outp = (float*)d_out;
    float* p_out = outp;                       // p1,p2 contiguous [1024,256]
    float* z_out = outp + (size_t)2 * NG * FPROJ;  // z1,z2 contiguous [1024,256]
    float* st1 = stats, *st2 = stats + 1024;
    hipMemsetAsync(stats, 0, 2048 * 4, stream);
    k_mlp<<<128, 256, 0, stream>>>(pooled, Wp1, bp1, t1,
                                   128, 256, 0, st1, nullptr, nullptr, nullptr);
    k_mlp<<<128, 256, 0, stream>>>(t1, Wp2, bp2, t2,
                                   256, 256, 0, st2, st1, g1, be1);
    k_bnapply<<<1024, 256, 0, stream>>>(t2, st2, g2, be2, z_out, 256, 0);
    k_mlp<<<128, 128, 0, stream>>>(z_out, Wq1, bq1, t3,
                                   256, 128, 1, nullptr, nullptr, nullptr, nullptr);
    k_mlp<<<128, 256, 0, stream>>>(t3, Wq2, bq2, p_out,
                                   128, 256, 0, nullptr, nullptr, nullptr, nullptr);
}

// Round 9
// 753.087 us; speedup vs baseline: 1.8435x; 1.0264x over previous
//
#include <hip/hip_runtime.h>
#include <hip/hip_bf16.h>

#define NN     50000
#define NN2    100000
#define NEDGE  1600000
#define NE2    3200000
#define NG     512
#define FIN    128
#define FHID   128
#define FPROJ  256

// merged radix CSR build params — 512-node coarse buckets
#define BSH    9              // bucket shift
#define BSZ    512            // nodes per bucket
#define NBUCK  98             // per-graph buckets (ceil 50000/512)
#define NBUCK2 196
#define EPB    8192
#define NABLK  196            // per-graph A-blocks
#define NABLK2 392
#define NHIST2 (NBUCK2*NABLK2)   // 76,832

typedef __attribute__((ext_vector_type(8))) short short8;
typedef __attribute__((ext_vector_type(4))) float f32x4;

static __device__ __forceinline__ short f2bf(float f) {
    union { float f; unsigned u; } x; x.f = f;
    unsigned r = (x.u + 0x7FFFu + ((x.u >> 16) & 1u)) >> 16;
    return (short)(r & 0xFFFFu);
}
static __device__ __forceinline__ float bf2f(unsigned short u) {
    union { unsigned u; float f; } x; x.u = ((unsigned)u) << 16;
    return x.f;
}
static __device__ __forceinline__ float bflo(unsigned u) {
    union { unsigned u; float f; } x; x.u = u << 16; return x.f;
}
static __device__ __forceinline__ float bfhi(unsigned u) {
    union { unsigned u; float f; } x; x.u = u & 0xFFFF0000u; return x.f;
}
static __device__ __forceinline__ unsigned packbf(float a, float b) {
    return (unsigned)(unsigned short)f2bf(a) | ((unsigned)(unsigned short)f2bf(b) << 16);
}

// ---------------- merged CSR build (both graphs, atomic-free at device scope) ----

__global__ __launch_bounds__(1024) void k_bhist(const int* __restrict__ dst0,
                                                const int* __restrict__ dst1,
                                                int* __restrict__ histG,
                                                unsigned short* __restrict__ lrank) {
    __shared__ int h[NBUCK2];
    for (int j = threadIdx.x; j < NBUCK2; j += 1024) h[j] = 0;
    __syncthreads();
    int b = blockIdx.x;                  // 0..391
    int g = b / NABLK, blk = b % NABLK;
    const int* dst = g ? dst1 : dst0;
    int base = blk * EPB;
    int gb = g * NBUCK;
    for (int t = threadIdx.x; t < EPB; t += 1024) {
        int i = base + t;
        if (i < NEDGE)
            lrank[(size_t)g * NEDGE + i] =
                (unsigned short)atomicAdd(&h[gb + (dst[i] >> BSH)], 1);
    }
    __syncthreads();
    for (int j = threadIdx.x; j < NBUCK2; j += 1024)
        histG[(size_t)j * NABLK2 + b] = h[j];
}

__global__ void s_scan256(const int* __restrict__ in, int* __restrict__ out,
                          int* __restrict__ bsum, int n) {
    __shared__ int s[256];
    int i = blockIdx.x * 256 + threadIdx.x;
    int v = (i < n) ? in[i] : 0;
    s[threadIdx.x] = v;
    for (int o = 1; o < 256; o <<= 1) {
        __syncthreads();
        int t = (threadIdx.x >= o) ? s[threadIdx.x - o] : 0;
        __syncthreads();
        s[threadIdx.x] += t;
    }
    __syncthreads();
    if (i < n) out[i] = s[threadIdx.x] - v;   // exclusive
    if (threadIdx.x == 255 && bsum) bsum[blockIdx.x] = s[255];
}

__global__ void s_add(int* __restrict__ out, const int* __restrict__ bs, int n) {
    int i = blockIdx.x * 256 + threadIdx.x;
    if (i < n) out[i] += bs[blockIdx.x];
}

__global__ __launch_bounds__(1024) void k_part(const int* __restrict__ src0,
                                               const int* __restrict__ dst0,
                                               const int* __restrict__ src1,
                                               const int* __restrict__ dst1,
                                               const unsigned short* __restrict__ lrank,
                                               const int* __restrict__ histS,
                                               unsigned* __restrict__ pedge) {
    int b = blockIdx.x;
    int g = b / NABLK, blk = b % NABLK;
    const int* src = g ? src1 : src0;
    const int* dst = g ? dst1 : dst0;
    int base = blk * EPB;
    int gb = g * NBUCK;
    for (int t = threadIdx.x; t < EPB; t += 1024) {
        int i = base + t;
        if (i < NEDGE) {
            int d = dst[i];
            int pos = histS[(size_t)(gb + (d >> BSH)) * NABLK2 + b]
                      + (int)lrank[(size_t)g * NEDGE + i];
            pedge[pos] = (unsigned)src[i] | ((unsigned)(d & (BSZ - 1)) << 16);
        }
    }
}

// one block per 512-node bucket -> fine CSR (ushort srcs) + csroff + dinv
__global__ __launch_bounds__(256) void k_csr(const unsigned* __restrict__ pedge,
                                             const int* __restrict__ histS,
                                             int* __restrict__ csroff,
                                             unsigned short* __restrict__ csrc,
                                             float* __restrict__ dinv) {
    __shared__ int cnt[BSZ], off[BSZ], cur[BSZ];
    int k = blockIdx.x;                  // 0..195
    int g = k / NBUCK;
    int nl0 = (k - g * NBUCK) * BSZ;     // local node base
    int beg = histS[(size_t)k * NABLK2];
    int end = (k == NBUCK2 - 1) ? NE2 : histS[(size_t)(k + 1) * NABLK2];
    for (int t = threadIdx.x; t < BSZ; t += 256) { cnt[t] = 0; cur[t] = 0; }
    __syncthreads();
    for (int e = beg + threadIdx.x; e < end; e += 256)
        atomicAdd(&cnt[(pedge[e] >> 16) & (BSZ - 1)], 1);
    __syncthreads();
    if (threadIdx.x == 0) {
        int s = 0;
        for (int j = 0; j < BSZ; ++j) { off[j] = s; s += cnt[j]; }
    }
    __syncthreads();
    for (int e = beg + threadIdx.x; e < end; e += 256) {
        unsigned v = pedge[e];
        int j = (v >> 16) & (BSZ - 1);
        int r = atomicAdd(&cur[j], 1);
        csrc[beg + off[j] + r] = (unsigned short)(v & 0xFFFFu);
    }
    __syncthreads();
    for (int t = threadIdx.x; t < BSZ; t += 256) {
        int nl = nl0 + t;
        if (nl < NN) {
            int gn = g * NN + nl;
            csroff[gn] = beg + off[t];
            dinv[gn] = 1.0f / sqrtf((float)(cnt[t] + 1));
        }
    }
    if (k == NBUCK2 - 1 && threadIdx.x == 0) csroff[NN2] = NE2;
}

// ---------------- MFMA GEMM over both graphs: hp[i,:] = bf16((A[i,:]@W)*dinv[i]) ----

__global__ void k_prepw(const float* __restrict__ W0, const float* __restrict__ W1,
                        const float* __restrict__ W2, short* __restrict__ Wf) {
    int b = blockIdx.x;                  // 96 blocks
    int l = b >> 5; b &= 31;
    const float* W = (l == 0) ? W0 : (l == 1) ? W1 : W2;
    int nt = b >> 2, kt = b & 3;
    int lane = threadIdx.x;
    int n = nt * 16 + (lane & 15);
    int kbase = kt * 32 + (lane >> 4) * 8;
    short8 v;
#pragma unroll
    for (int j = 0; j < 8; ++j) v[j] = f2bf(W[(kbase + j) * FHID + n]);
    *(short8*)(Wf + (size_t)l * 16384 + (size_t)((nt * 4 + kt) * 64 + lane) * 8) = v;
}

__global__ __launch_bounds__(256) void k_gemm(const float* __restrict__ x1,
                                              const float* __restrict__ x2,
                                              const unsigned short* __restrict__ Abf,
                                              const short* __restrict__ Wf,
                                              const float* __restrict__ dinv,
                                              unsigned short* __restrict__ hp) {
    int lane = threadIdx.x & 63;
    int wv = threadIdx.x >> 6;
    int quad = lane >> 4;
    int rowbase = blockIdx.x * 64 + wv * 16;    // 1564 blocks -> 100,096 rows
    int arow = rowbase + (lane & 15);
    if (arow >= NN2) arow = NN2 - 1;

    f32x4 acc[8];
#pragma unroll
    for (int i = 0; i < 8; ++i) acc[i] = (f32x4){0.f, 0.f, 0.f, 0.f};

#pragma unroll
    for (int kt = 0; kt < 4; ++kt) {
        short8 af;
        if (Abf) {
            af = *(const short8*)(Abf + (size_t)arow * FIN + kt * 32 + quad * 8);
        } else {
            const float* ap = (arow < NN ? x1 + (size_t)arow * FIN
                                         : x2 + (size_t)(arow - NN) * FIN)
                              + kt * 32 + quad * 8;
            float4 a0 = *(const float4*)ap;
            float4 a1 = *(const float4*)(ap + 4);
            af[0] = f2bf(a0.x); af[1] = f2bf(a0.y); af[2] = f2bf(a0.z); af[3] = f2bf(a0.w);
            af[4] = f2bf(a1.x); af[5] = f2bf(a1.y); af[6] = f2bf(a1.z); af[7] = f2bf(a1.w);
        }
#pragma unroll
        for (int nt = 0; nt < 8; ++nt) {
            short8 bf = *(const short8*)(Wf + (size_t)((nt * 4 + kt) * 64 + lane) * 8);
            acc[nt] = __builtin_amdgcn_mfma_f32_16x16x32_bf16(af, bf, acc[nt], 0, 0, 0);
        }
    }
    // C/D layout: col = lane&15, row = quad*4 + reg   [measured m89/m91]
    float4 dv = *(const float4*)(dinv + rowbase + quad * 4);
    float dvv[4] = {dv.x, dv.y, dv.z, dv.w};
    int col = lane & 15;
#pragma unroll
    for (int r = 0; r < 4; ++r) {
        int orow = rowbase + quad * 4 + r;
        if (orow < NN2) {
#pragma unroll
            for (int nt = 0; nt < 8; ++nt)
                hp[(size_t)orow * FHID + nt * 16 + col] =
                    (unsigned short)f2bf(acc[nt][r] * dvv[r]);
        }
    }
}

// ------- Aggregate full 128-feature row, per graph (pointers pre-offset host-side)

__global__ __launch_bounds__(256) void k_agg(const uint2* __restrict__ hp,
                                             const int* __restrict__ off,
                                             const unsigned short* __restrict__ csrc,
                                             const float* __restrict__ dinv,
                                             const float* __restrict__ bias,
                                             const unsigned short* __restrict__ resid,
                                             unsigned short* __restrict__ hout) {
    int tid = threadIdx.x;
    int l2 = tid & 31;                        // 4 feats per lane -> 128 feats
    int node = blockIdx.x * 8 + (tid >> 5);   // 6250 blocks * 8 = 50000 exactly
    int beg = off[node], end = off[node + 1];

    uint2 sv = hp[(size_t)node * 32 + l2];
    float a0 = bflo(sv.x), a1 = bfhi(sv.x), a2 = bflo(sv.y), a3 = bfhi(sv.y);

    int e = beg;
    for (; e + 16 <= end; e += 16) {
        int s[16];
#pragma unroll
        for (int j = 0; j < 16; ++j) s[j] = (int)csrc[e + j];
        uint2 v[16];
#pragma unroll
        for (int j = 0; j < 16; ++j) v[j] = hp[(size_t)s[j] * 32 + l2];
#pragma unroll
        for (int j = 0; j < 16; ++j) {
            a0 += bflo(v[j].x); a1 += bfhi(v[j].x);
            a2 += bflo(v[j].y); a3 += bfhi(v[j].y);
        }
    }
    for (; e + 4 <= end; e += 4) {
        int s[4];
#pragma unroll
        for (int j = 0; j < 4; ++j) s[j] = (int)csrc[e + j];
        uint2 v[4];
#pragma unroll
        for (int j = 0; j < 4; ++j) v[j] = hp[(size_t)s[j] * 32 + l2];
#pragma unroll
        for (int j = 0; j < 4; ++j) {
            a0 += bflo(v[j].x); a1 += bfhi(v[j].x);
            a2 += bflo(v[j].y); a3 += bfhi(v[j].y);
        }
    }
    for (; e < end; ++e) {
        uint2 v = hp[(size_t)csrc[e] * 32 + l2];
        a0 += bflo(v.x); a1 += bfhi(v.x);
        a2 += bflo(v.y); a3 += bfhi(v.y);
    }
    float dv = dinv[node];
    float4 b = ((const float4*)bias)[l2];
    float o0 = fmaxf(a0 * dv + b.x, 0.f);
    float o1 = fmaxf(a1 * dv + b.y, 0.f);
    float o2 = fmaxf(a2 * dv + b.z, 0.f);
    float o3 = fmaxf(a3 * dv + b.w, 0.f);
    if (resid) {
        uint2 rv = ((const uint2*)resid)[(size_t)node * 32 + l2];
        o0 += bflo(rv.x); o1 += bfhi(rv.x);
        o2 += bflo(rv.y); o3 += bfhi(rv.y);
    }
    uint2 ov;
    ov.x = packbf(o0, o1);
    ov.y = packbf(o2, o3);
    ((uint2*)hout)[(size_t)node * 32 + l2] = ov;
}

// ---------------- Pooling (both graphs) ----------------

__global__ void k_starts(const int* __restrict__ b0, const int* __restrict__ b1,
                         int* __restrict__ starts) {
    int blk = blockIdx.x;                 // 392 blocks
    int g = blk / NABLK;
    int i = (blk - g * NABLK) * 256 + threadIdx.x;
    if (i >= NN) return;
    const int* batch = g ? b1 : b0;
    int* st = starts + g * (NG + 1);
    int b = batch[i];
    if (i == 0) {
        for (int q = 0; q <= b; ++q) st[q] = 0;
    } else {
        int p = batch[i - 1];
        for (int q = p + 1; q <= b; ++q) st[q] = i;
    }
    if (i == NN - 1) {
        for (int q = b + 1; q <= NG; ++q) st[q] = NN;
    }
}

__global__ void k_pool(const unsigned short* __restrict__ h, const int* __restrict__ starts,
                       float* __restrict__ pooled) {
    int b = blockIdx.x;                  // 1024 blocks
    int g = b >> 9, lg = b & 511;
    int c = threadIdx.x;                 // 128 threads
    const int* st = starts + g * (NG + 1);
    const unsigned short* hb = h + (size_t)g * NN * FHID;
    int beg = st[lg], end = st[lg + 1];
    float s = 0.f;
    for (int i = beg; i < end; ++i) s += bf2f(hb[(size_t)i * FHID + c]);
    int cnt = end - beg;
    pooled[(size_t)b * FHID + c] = s / (float)(cnt > 0 ? cnt : 1);
}

// ---------------- Fused MLP / BN heads (1024 rows = both graphs) ----------------

__global__ void k_mlp(const float* __restrict__ A, const float* __restrict__ W,
                      const float* __restrict__ bias, float* __restrict__ out,
                      int K, int Nc, int act,
                      float* __restrict__ statsOut,
                      const float* __restrict__ statsIn,
                      const float* __restrict__ gIn, const float* __restrict__ beIn) {
    __shared__ float As[8 * 256];
    __shared__ float scl[256], shf[256];
    int n = threadIdx.x;                 // blockDim.x == Nc
    int r0 = blockIdx.x * 8;             // 128 blocks -> 1024 rows
    int g = blockIdx.x >> 6;
    if (statsIn && n < K) {
        const float* si = statsIn + g * 512;
        float m = si[n] * (1.f / 512.f);
        float var = si[K + n] * (1.f / 512.f) - m * m;
        float inv = 1.0f / sqrtf(var + 1e-5f);
        float s = gIn[n] * inv;
        scl[n] = s;
        shf[n] = beIn[n] - m * s;
    }
    __syncthreads();
    for (int idx = n; idx < 8 * K; idx += blockDim.x) {
        float v = A[(size_t)r0 * K + idx];
        if (statsIn) {
            int k = idx & (K - 1);       // K is 128 or 256
            v = fmaxf(v * scl[k] + shf[k], 0.f);   // relu(BN(.)) input transform
        }
        As[idx] = v;
    }
    __syncthreads();
    float bb = bias[n];
    float acc[8];
#pragma unroll
    for (int r = 0; r < 8; ++r) acc[r] = bb;
    for (int k = 0; k < K; ++k) {
        float w = W[(size_t)k * Nc + n];
#pragma unroll
        for (int r = 0; r < 8; ++r) acc[r] = fmaf(As[r * K + k], w, acc[r]);
    }
    if (statsOut) {
        float s = 0.f, q = 0.f;
#pragma unroll
        for (int r = 0; r < 8; ++r) { s += acc[r]; q += acc[r] * acc[r]; }
        atomicAdd(&statsOut[g * 512 + n], s);
        atomicAdd(&statsOut[g * 512 + Nc + n], q);
    }
#pragma unroll
    for (int r = 0; r < 8; ++r) {
        float v = acc[r];
        if (act) v = fmaxf(v, 0.f);
        out[(size_t)(r0 + r) * Nc + n] = v;
    }
}

__global__ void k_bnapply(const float* __restrict__ X, const float* __restrict__ stats,
                          const float* __restrict__ gamma, const float* __restrict__ beta,
                          float* __restrict__ out, int Nc, int act) {
    int i = blockIdx.x * 256 + threadIdx.x;          // 1024*Nc elements
    if (i >= 1024 * Nc) return;
    int c = i % Nc;
    int g = i / (512 * Nc);
    const float* st = stats + g * 512;
    float m = st[c] * (1.f / 512.f);
    float var = st[Nc + c] * (1.f / 512.f) - m * m;
    float inv = 1.0f / sqrtf(var + 1e-5f);
    float v = gamma[c] * (X[i] - m) * inv + beta[c];
    if (act) v = fmaxf(v, 0.f);
    out[i] = v;
}

// ---------------- Orchestration ----------------

extern "C" void kernel_launch(void* const* d_in, const int* in_sizes, int n_in,
                              void* d_out, int out_size, void* d_ws, size_t ws_size,
                              hipStream_t stream) {
    const float* x1 = (const float*)d_in[0];
    const float* x2 = (const float*)d_in[3];
    const int*   ei[2]    = {(const int*)d_in[1], (const int*)d_in[4]};
    const int*   batch[2] = {(const int*)d_in[2], (const int*)d_in[5]};
    const float* W[3]  = {(const float*)d_in[6], (const float*)d_in[8], (const float*)d_in[10]};
    const float* bb[3] = {(const float*)d_in[7], (const float*)d_in[9], (const float*)d_in[11]};
    const float* Wp1 = (const float*)d_in[12]; const float* bp1 = (const float*)d_in[13];
    const float* g1  = (const float*)d_in[14]; const float* be1 = (const float*)d_in[15];
    const float* Wp2 = (const float*)d_in[16]; const float* bp2 = (const float*)d_in[17];
    const float* g2  = (const float*)d_in[18]; const float* be2 = (const float*)d_in[19];
    const float* Wq1 = (const float*)d_in[20]; const float* bq1 = (const float*)d_in[21];
    const float* Wq2 = (const float*)d_in[22]; const float* bq2 = (const float*)d_in[23];

    char* ws = (char*)d_ws;
    size_t off = 0;
    auto alloc = [&](size_t bytes) -> void* {
        void* p = ws + off;
        off += (bytes + 255) & ~(size_t)255;
        return p;
    };
    unsigned short* h_cur  = (unsigned short*)alloc((size_t)NN2 * FHID * 2);  // bf16 state
    unsigned short* hp     = (unsigned short*)alloc((size_t)NN2 * FHID * 2);  // bf16 pre-agg
    unsigned short* csrc   = (unsigned short*)alloc((size_t)NE2 * 2);
    int*            csroff = (int*)alloc((size_t)(NN2 + 1) * 4);
    unsigned short* lrank  = (unsigned short*)alloc((size_t)NE2 * 2);
    unsigned*       pedge  = (unsigned*)alloc((size_t)NE2 * 4);
    int*            histG  = (int*)alloc((size_t)NHIST2 * 4);
    int*            histS  = (int*)alloc((size_t)NHIST2 * 4);
    int*            bsum1  = (int*)alloc(512 * 4);
    int*            bsum1s = (int*)alloc(512 * 4);
    int*            bsum2  = (int*)alloc(256 * 4);
    int*            bsum2s = (int*)alloc(256 * 4);
    float*          dinv   = (float*)alloc((size_t)100352 * 4);  // padded for gemm epilogue
    int*            starts = (int*)alloc(2 * (NG + 1) * 4);
    float*          pooled = (float*)alloc((size_t)2 * NG * FHID * 4);
    short*          Wf     = (short*)alloc((size_t)3 * 16384 * 2);
    float*          t1     = (float*)alloc((size_t)1024 * 256 * 4);
    float*          t2     = (float*)alloc((size_t)1024 * 256 * 4);
    float*          t3     = (float*)alloc((size_t)1024 * 128 * 4);
    float*          stats  = (float*)alloc(2048 * 4);  // [st1: 2g x 512][st2: 2g x 512]

    const int* src0 = ei[0];           const int* dst0 = ei[0] + NEDGE;
    const int* src1 = ei[1];           const int* dst1 = ei[1] + NEDGE;

    k_prepw<<<96, 64, 0, stream>>>(W[0], W[1], W[2], Wf);

    // merged atomic-free radix CSR build (both graphs), 512-node buckets
    const int nsb1 = (NHIST2 + 255) / 256;        // 301
    const int nsb2 = (nsb1 + 255) / 256;          // 2
    k_bhist<<<NABLK2, 1024, 0, stream>>>(dst0, dst1, histG, lrank);
    s_scan256<<<nsb1, 256, 0, stream>>>(histG, histS, bsum1, NHIST2);
    s_scan256<<<nsb2, 256, 0, stream>>>(bsum1, bsum1s, bsum2, nsb1);
    s_scan256<<<1, 256, 0, stream>>>(bsum2, bsum2s, nullptr, nsb2);
    s_add<<<nsb2, 256, 0, stream>>>(bsum1s, bsum2s, nsb1);
    s_add<<<nsb1, 256, 0, stream>>>(histS, bsum1s, NHIST2);
    k_part<<<NABLK2, 1024, 0, stream>>>(src0, dst0, src1, dst1, lrank, histS, pedge);
    k_csr<<<NBUCK2, 256, 0, stream>>>(pedge, histS, csroff, csrc, dinv);

    // encoder: merged gemm, per-graph aggregation
    for (int l = 0; l < 3; ++l) {
        const unsigned short* Abf = (l == 0) ? nullptr : h_cur;
        k_gemm<<<1564, 256, 0, stream>>>(x1, x2, Abf, Wf + (size_t)l * 16384, dinv, hp);
        for (int g = 0; g < 2; ++g) {
            size_t nb = (size_t)g * NN;
            const unsigned short* resid = (l == 0) ? nullptr : h_cur + nb * FHID;
            k_agg<<<6250, 256, 0, stream>>>((const uint2*)(hp + nb * FHID),
                                            csroff + nb, csrc, dinv + nb,
                                            bb[l], resid, h_cur + nb * FHID);
        }
    }
    k_starts<<<NABLK2, 256, 0, stream>>>(batch[0], batch[1], starts);
    k_pool<<<1024, 128, 0, stream>>>(h_cur, starts, pooled);

    // merged heads (1024 rows, per-graph BN stats)
    float* outp = (float*)d_out;
    float* p_out = outp;                       // p1,p2 contiguous [1024,256]
    float* z_out = outp + (size_t)2 * NG * FPROJ;  // z1,z2 contiguous [1024,256]
    float* st1 = stats, *st2 = stats + 1024;
    hipMemsetAsync(stats, 0, 2048 * 4, stream);
    k_mlp<<<128, 256, 0, stream>>>(pooled, Wp1, bp1, t1,
                                   128, 256, 0, st1, nullptr, nullptr, nullptr);
    k_mlp<<<128, 256, 0, stream>>>(t1, Wp2, bp2, t2,
                                   256, 256, 0, st2, st1, g1, be1);
    k_bnapply<<<1024, 256, 0, stream>>>(t2, st2, g2, be2, z_out, 256, 0);
    k_mlp<<<128, 128, 0, stream>>>(z_out, Wq1, bq1, t3,
                                   256, 128, 1, nullptr, nullptr, nullptr, nullptr);
    k_mlp<<<128, 256, 0, stream>>>(t3, Wq2, bq2, p_out,
                                   128, 256, 0, nullptr, nullptr, nullptr, nullptr);
}